// Round 1
// baseline (2565.566 us; speedup 1.0000x reference)
//
#include <hip/hip_runtime.h>
#include <hip/hip_bf16.h>
#include <math.h>

// ---------------------------------------------------------------------------
// FaceAttnProcessor forward, fp32 correctness-first baseline.
// B=2, N=1024, C=768, H=12, d=64, L=93 (text=77, face=16), INNER=3072.
//
// Pipeline:
//  1. comb = [LN(x); LN(face)]                (B,1040,768)
//  2. q/k/v = comb @ sa_w{q,k,v}              (2080,768) each
//  3. self-attn (flash, Nk=1040, q rows 0..1023)  -> attn (2048,768)
//  4. x1 = x + tanh(a_attn)*(attn @ sa_wo + b)
//  5. hh = LN(LN(x1; ln2); ff_ln)
//  6. t = hh @ ff_w1                          (2048,6144)
//  7. g = t[:, :3072] * gelu(t[:, 3072:])     (2048,3072)
//  8. x2 = x1 + tanh(a_dense)*(g @ ff_w2)
//  9. text gather (154,768); q2 = x2@ca_wq; k2/v2 = text@ca_w{k,v}
// 10. cross-attn (Nk=77) -> attn2
// 11. out = x2 + (attn2 @ ca_wo + b)
// ---------------------------------------------------------------------------

#define C_DIM 768
#define B_DIM 2
#define N_DIM 1024
#define NC_DIM 1040   // 1024 + 16 face tokens
#define L_DIM 93
#define TEXT_LEN 77
#define INNER 3072

// Workspace offsets (floats). Phase-based reuse; total ~94.6 MB.
#define OFF_COMB  0u          // 2*1040*768 = 1,597,440
#define OFF_Q     1600000u
#define OFF_K     3200000u
#define OFF_V     4800000u
#define OFF_ATTN  6400000u    // 2*1024*768 = 1,572,864
#define OFF_HH    0u          // phase 2 (comb dead)
#define OFF_T     1600000u    // 2*1024*6144 = 12,582,912 (q/k/v/attn dead)
#define OFF_G     14200000u   // 2*1024*3072 = 6,291,456
#define OFF_X1    20500000u   // persistent
#define OFF_X2    22080000u   // persistent
#define OFF_Q2    0u          // phase 3 (hh dead)
#define OFF_TEXT  1600000u    // (t dead)
#define OFF_K2    1750000u
#define OFF_V2    1900000u
#define OFF_ATTN2 2100000u

// ---------------- block reduction (256 threads = 4 waves) -----------------
__device__ __forceinline__ float block_sum(float v, float* sh) {
#pragma unroll
  for (int o = 32; o > 0; o >>= 1) v += __shfl_down(v, o);
  int lane = threadIdx.x & 63, w = threadIdx.x >> 6;
  if (lane == 0) sh[w] = v;
  __syncthreads();
  float r = sh[0] + sh[1] + sh[2] + sh[3];
  __syncthreads();   // protect sh reuse by a subsequent call
  return r;
}

// ---------------- LN(x) and LN(face) -> comb ------------------------------
__global__ __launch_bounds__(256)
void ln_concat_kernel(const float* __restrict__ x, const float* __restrict__ enc,
                      const float* __restrict__ g, const float* __restrict__ b,
                      float* __restrict__ comb) {
  __shared__ float sh[4];
  int r = blockIdx.x;                 // 0 .. B*1040-1
  int bb = r / NC_DIM, i = r % NC_DIM;
  const float* src = (i < N_DIM)
      ? (x   + ((size_t)bb * N_DIM + i) * C_DIM)
      : (enc + ((size_t)bb * L_DIM + TEXT_LEN + (i - N_DIM)) * C_DIM);
  float v[3];
#pragma unroll
  for (int j = 0; j < 3; ++j) v[j] = src[threadIdx.x + j * 256];
  float mean = block_sum(v[0] + v[1] + v[2], sh) * (1.f / C_DIM);
  float sq = 0.f;
#pragma unroll
  for (int j = 0; j < 3; ++j) { float d = v[j] - mean; sq += d * d; }
  float var = block_sum(sq, sh) * (1.f / C_DIM);
  float rstd = rsqrtf(var + 1e-5f);
  float* dst = comb + (size_t)r * C_DIM;
#pragma unroll
  for (int j = 0; j < 3; ++j) {
    int c = threadIdx.x + j * 256;
    dst[c] = (v[j] - mean) * rstd * g[c] + b[c];
  }
}

// ---------------- double layernorm: LN(LN(src; g1,b1); g2,b2) -------------
__global__ __launch_bounds__(256)
void ln_double_kernel(const float* __restrict__ src,
                      const float* __restrict__ g1, const float* __restrict__ b1,
                      const float* __restrict__ g2, const float* __restrict__ b2,
                      float* __restrict__ out) {
  __shared__ float sh[4];
  const float* s = src + (size_t)blockIdx.x * C_DIM;
  float v[3];
#pragma unroll
  for (int j = 0; j < 3; ++j) v[j] = s[threadIdx.x + j * 256];
  float mean = block_sum(v[0] + v[1] + v[2], sh) * (1.f / C_DIM);
  float sq = 0.f;
#pragma unroll
  for (int j = 0; j < 3; ++j) { float d = v[j] - mean; sq += d * d; }
  float rstd = rsqrtf(block_sum(sq, sh) * (1.f / C_DIM) + 1e-5f);
  float y[3];
#pragma unroll
  for (int j = 0; j < 3; ++j) {
    int c = threadIdx.x + j * 256;
    y[j] = (v[j] - mean) * rstd * g1[c] + b1[c];
  }
  float mean2 = block_sum(y[0] + y[1] + y[2], sh) * (1.f / C_DIM);
  sq = 0.f;
#pragma unroll
  for (int j = 0; j < 3; ++j) { float d = y[j] - mean2; sq += d * d; }
  float rstd2 = rsqrtf(block_sum(sq, sh) * (1.f / C_DIM) + 1e-5f);
  float* dst = out + (size_t)blockIdx.x * C_DIM;
#pragma unroll
  for (int j = 0; j < 3; ++j) {
    int c = threadIdx.x + j * 256;
    dst[c] = (y[j] - mean2) * rstd2 * g2[c] + b2[c];
  }
}

// ---------------- generic tiled SGEMM with fused epilogue ------------------
// Out[M,N] = epilogue(A[M,K] @ W[K,N])
//   val = acc + bias[n]                       (if bias)
//   val = res[m,n] + tanh(*alphaPtr) * val    (if res; alphaPtr null -> f=1)
#define BM 64
#define BN 64
#define BK 16
__global__ __launch_bounds__(256)
void gemm_kernel(const float* __restrict__ A, const float* __restrict__ W,
                 float* __restrict__ Out, int M, int N, int K,
                 const float* __restrict__ bias, const float* __restrict__ res,
                 const float* __restrict__ alphaPtr) {
  __shared__ float As[BK][BM + 4];   // +4 pad: keep 16B alignment, break bank stride
  __shared__ float Bs[BK][BN + 4];
  int t = threadIdx.x;
  int tx = t & 15, ty = t >> 4;
  int n0 = blockIdx.x * BN, m0 = blockIdx.y * BM;
  float c[4][4] = {};
  for (int k0 = 0; k0 < K; k0 += BK) {
#pragma unroll
    for (int l = 0; l < 4; ++l) {          // A tile: 64 rows x 16 k
      int e = t + l * 256;
      int m = e >> 4, kk = e & 15;
      int gm = m0 + m;
      As[kk][m] = (gm < M) ? A[(size_t)gm * K + k0 + kk] : 0.f;
    }
#pragma unroll
    for (int l = 0; l < 4; ++l) {          // B tile: 16 k x 64 cols
      int e = t + l * 256;
      int kk = e >> 6, n = e & 63;
      Bs[kk][n] = W[(size_t)(k0 + kk) * N + n0 + n];
    }
    __syncthreads();
#pragma unroll
    for (int kk = 0; kk < BK; ++kk) {
      float a[4], bvec[4];
#pragma unroll
      for (int j = 0; j < 4; ++j) a[j] = As[kk][ty * 4 + j];
#pragma unroll
      for (int i = 0; i < 4; ++i) bvec[i] = Bs[kk][tx * 4 + i];
#pragma unroll
      for (int j = 0; j < 4; ++j)
#pragma unroll
        for (int i = 0; i < 4; ++i) c[j][i] += a[j] * bvec[i];
    }
    __syncthreads();
  }
  float f = alphaPtr ? tanhf(alphaPtr[0]) : 1.0f;
#pragma unroll
  for (int j = 0; j < 4; ++j) {
    int gm = m0 + ty * 4 + j;
    if (gm >= M) continue;
#pragma unroll
    for (int i = 0; i < 4; ++i) {
      int gn = n0 + tx * 4 + i;
      float val = c[j][i];
      if (bias) val += bias[gn];
      if (res)  val = res[(size_t)gm * N + gn] + f * val;
      Out[(size_t)gm * N + gn] = val;
    }
  }
}

// ---------------- flash attention -----------------------------------------
// One block = one (b, h, 64-query tile). Online softmax over key tiles of 64.
// Q: (B*q_rows_per_b, 768) head-interleaved; K/V: (B*kv_rows_per_b, 768).
// O: (B*1024, 768). Only first 1024 queries per batch are processed.
__global__ __launch_bounds__(256)
void attn_kernel(const float* __restrict__ Q, const float* __restrict__ K,
                 const float* __restrict__ V, float* __restrict__ O,
                 int q_rows_per_b, int kv_rows_per_b, int Nk) {
  __shared__ float qs[64][68];
  __shared__ float ks[64][68];   // holds K tile, then reused for V tile
  __shared__ float ss[64][68];
  __shared__ float mrow[64], lrow[64], arow[64];
  const float scale = 0.125f;    // 64^-0.5
  int t = threadIdx.x;
  int b = blockIdx.z, h = blockIdx.y, q0 = blockIdx.x * 64;
#pragma unroll
  for (int l = 0; l < 16; ++l) {
    int e = t + l * 256; int r = e >> 6, c = e & 63;
    qs[r][c] = Q[((size_t)(b * q_rows_per_b + q0 + r)) * C_DIM + h * 64 + c];
  }
  if (t < 64) { mrow[t] = -INFINITY; lrow[t] = 0.f; }
  float acc[16];
#pragma unroll
  for (int i = 0; i < 16; ++i) acc[i] = 0.f;
  int qr = t >> 2, dbase = (t & 3) * 16;
  int ntiles = (Nk + 63) >> 6;
  for (int kt = 0; kt < ntiles; ++kt) {
#pragma unroll
    for (int l = 0; l < 16; ++l) {                      // K tile
      int e = t + l * 256; int r = e >> 6, c = e & 63;
      int kj = kt * 64 + r;
      ks[r][c] = (kj < Nk)
          ? K[((size_t)(b * kv_rows_per_b + kj)) * C_DIM + h * 64 + c] : 0.f;
    }
    __syncthreads();
#pragma unroll
    for (int i = 0; i < 16; ++i) {                      // 16 scores/thread
      int kl = dbase + i;
      float s = 0.f;
      for (int d = 0; d < 64; ++d) s += qs[qr][d] * ks[kl][d];
      ss[qr][kl] = (kt * 64 + kl < Nk) ? s * scale : -INFINITY;
    }
    __syncthreads();
#pragma unroll
    for (int l = 0; l < 16; ++l) {                      // V tile (reuse ks)
      int e = t + l * 256; int r = e >> 6, c = e & 63;
      int kj = kt * 64 + r;
      ks[r][c] = (kj < Nk)
          ? V[((size_t)(b * kv_rows_per_b + kj)) * C_DIM + h * 64 + c] : 0.f;
    }
    if (t < 64) {                                       // online softmax, 1 row/thread
      int r = t;
      float mx = mrow[r];
      for (int j = 0; j < 64; ++j) mx = fmaxf(mx, ss[r][j]);
      float a = expf(mrow[r] - mx);
      float sum = 0.f;
      for (int j = 0; j < 64; ++j) {
        float p = expf(ss[r][j] - mx); ss[r][j] = p; sum += p;
      }
      lrow[r] = lrow[r] * a + sum;
      mrow[r] = mx; arow[r] = a;
    }
    __syncthreads();
    float a = arow[qr];
#pragma unroll
    for (int i = 0; i < 16; ++i) acc[i] *= a;
    for (int j = 0; j < 64; ++j) {
      float p = ss[qr][j];
#pragma unroll
      for (int i = 0; i < 16; ++i) acc[i] += p * ks[j][dbase + i];
    }
    __syncthreads();
  }
  float inv = 1.f / lrow[qr];
#pragma unroll
  for (int i = 0; i < 16; ++i)
    O[((size_t)(b * N_DIM + q0 + qr)) * C_DIM + h * 64 + dbase + i] = acc[i] * inv;
}

// ---------------- GEGLU: g = a * gelu_exact(gate) --------------------------
__global__ __launch_bounds__(256)
void geglu_kernel(const float* __restrict__ tbuf, float* __restrict__ g) {
  int idx = blockIdx.x * 256 + threadIdx.x;          // 0 .. 2048*3072-1
  int r = idx / INNER, c = idx % INNER;
  float a = tbuf[(size_t)r * (2 * INNER) + c];
  float x = tbuf[(size_t)r * (2 * INNER) + INNER + c];
  float ge = 0.5f * x * (1.f + erff(x * 0.70710678118654752f));
  g[idx] = a * ge;
}

// ---------------- text gather: enc[:, :77] -> compact (154,768) ------------
__global__ __launch_bounds__(256)
void gather_text_kernel(const float* __restrict__ enc, float* __restrict__ out) {
  int r = blockIdx.x;                      // 0..153
  int bb = r / TEXT_LEN, j = r % TEXT_LEN;
  const float* src = enc + ((size_t)bb * L_DIM + j) * C_DIM;
  float* dst = out + (size_t)r * C_DIM;
#pragma unroll
  for (int l = 0; l < 3; ++l) {
    int c = threadIdx.x + l * 256;
    dst[c] = src[c];
  }
}

// ---------------------------------------------------------------------------
extern "C" void kernel_launch(void* const* d_in, const int* in_sizes, int n_in,
                              void* d_out, int out_size, void* d_ws, size_t ws_size,
                              hipStream_t stream) {
  const float* x        = (const float*)d_in[0];
  const float* enc      = (const float*)d_in[1];
  const float* ln1_g    = (const float*)d_in[2];
  const float* ln1_b    = (const float*)d_in[3];
  const float* ln2_g    = (const float*)d_in[4];
  const float* ln2_b    = (const float*)d_in[5];
  const float* sa_wq    = (const float*)d_in[6];
  const float* sa_wk    = (const float*)d_in[7];
  const float* sa_wv    = (const float*)d_in[8];
  const float* sa_wo    = (const float*)d_in[9];
  const float* sa_wo_b  = (const float*)d_in[10];
  const float* ff_ln_g  = (const float*)d_in[11];
  const float* ff_ln_b  = (const float*)d_in[12];
  const float* ff_w1    = (const float*)d_in[13];
  const float* ff_w2    = (const float*)d_in[14];
  const float* a_attn   = (const float*)d_in[15];
  const float* a_dense  = (const float*)d_in[16];
  const float* ca_wq    = (const float*)d_in[17];
  const float* ca_wk    = (const float*)d_in[18];
  const float* ca_wv    = (const float*)d_in[19];
  const float* ca_wo    = (const float*)d_in[20];
  const float* ca_wo_b  = (const float*)d_in[21];

  float* ws = (float*)d_ws;
  float* comb  = ws + OFF_COMB;
  float* q     = ws + OFF_Q;
  float* k     = ws + OFF_K;
  float* v     = ws + OFF_V;
  float* attn  = ws + OFF_ATTN;
  float* hh    = ws + OFF_HH;
  float* tbuf  = ws + OFF_T;
  float* g     = ws + OFF_G;
  float* x1    = ws + OFF_X1;
  float* x2    = ws + OFF_X2;
  float* q2    = ws + OFF_Q2;
  float* text  = ws + OFF_TEXT;
  float* k2    = ws + OFF_K2;
  float* v2    = ws + OFF_V2;
  float* attn2 = ws + OFF_ATTN2;
  float* out   = (float*)d_out;

  const int Mc = B_DIM * NC_DIM;   // 2080
  const int Mx = B_DIM * N_DIM;    // 2048
  const int Mt = B_DIM * TEXT_LEN; // 154

  auto gemm_grid = [](int M, int N) { return dim3(N / BN, (M + BM - 1) / BM); };

  // 1. LN + concat
  ln_concat_kernel<<<Mc, 256, 0, stream>>>(x, enc, ln1_g, ln1_b, comb);
  // 2. q/k/v projections (no bias)
  gemm_kernel<<<gemm_grid(Mc, C_DIM), 256, 0, stream>>>(comb, sa_wq, q, Mc, C_DIM, C_DIM, nullptr, nullptr, nullptr);
  gemm_kernel<<<gemm_grid(Mc, C_DIM), 256, 0, stream>>>(comb, sa_wk, k, Mc, C_DIM, C_DIM, nullptr, nullptr, nullptr);
  gemm_kernel<<<gemm_grid(Mc, C_DIM), 256, 0, stream>>>(comb, sa_wv, v, Mc, C_DIM, C_DIM, nullptr, nullptr, nullptr);
  // 3. self-attention (queries 0..1023, keys 0..1039)
  attn_kernel<<<dim3(N_DIM / 64, 12, B_DIM), 256, 0, stream>>>(q, k, v, attn, NC_DIM, NC_DIM, NC_DIM);
  // 4. x1 = x + tanh(a_attn)*(attn @ sa_wo + sa_wo_b)
  gemm_kernel<<<gemm_grid(Mx, C_DIM), 256, 0, stream>>>(attn, sa_wo, x1, Mx, C_DIM, C_DIM, sa_wo_b, x, a_attn);
  // 5. hh = LN(LN(x1; ln2); ff_ln)
  ln_double_kernel<<<Mx, 256, 0, stream>>>(x1, ln2_g, ln2_b, ff_ln_g, ff_ln_b, hh);
  // 6. t = hh @ ff_w1
  gemm_kernel<<<gemm_grid(Mx, 2 * INNER), 256, 0, stream>>>(hh, ff_w1, tbuf, Mx, 2 * INNER, C_DIM, nullptr, nullptr, nullptr);
  // 7. GEGLU
  geglu_kernel<<<(Mx * INNER) / 256, 256, 0, stream>>>(tbuf, g);
  // 8. x2 = x1 + tanh(a_dense)*(g @ ff_w2)
  gemm_kernel<<<gemm_grid(Mx, C_DIM), 256, 0, stream>>>(g, ff_w2, x2, Mx, C_DIM, INNER, nullptr, x1, a_dense);
  // 9. cross-attn inputs
  gather_text_kernel<<<Mt, 256, 0, stream>>>(enc, text);
  gemm_kernel<<<gemm_grid(Mx, C_DIM), 256, 0, stream>>>(x2, ca_wq, q2, Mx, C_DIM, C_DIM, nullptr, nullptr, nullptr);
  gemm_kernel<<<gemm_grid(Mt, C_DIM), 256, 0, stream>>>(text, ca_wk, k2, Mt, C_DIM, C_DIM, nullptr, nullptr, nullptr);
  gemm_kernel<<<gemm_grid(Mt, C_DIM), 256, 0, stream>>>(text, ca_wv, v2, Mt, C_DIM, C_DIM, nullptr, nullptr, nullptr);
  // 10. cross-attention (Nk=77)
  attn_kernel<<<dim3(N_DIM / 64, 12, B_DIM), 256, 0, stream>>>(q2, k2, v2, attn2, N_DIM, TEXT_LEN, TEXT_LEN);
  // 11. out = x2 + attn2 @ ca_wo + ca_wo_b
  gemm_kernel<<<gemm_grid(Mx, C_DIM), 256, 0, stream>>>(attn2, ca_wo, out, Mx, C_DIM, C_DIM, ca_wo_b, x2, nullptr);
}

// Round 2
// 1722.724 us; speedup vs baseline: 1.4892x; 1.4892x over previous
//
#include <hip/hip_runtime.h>
#include <hip/hip_bf16.h>
#include <math.h>

// ---------------------------------------------------------------------------
// FaceAttnProcessor forward. R1: register-tiled fp32 flash attention
// (64x64 GEMM tiles, float4 LDS, shuffle softmax). GEMMs unchanged from R0.
// B=2, N=1024, C=768, H=12, d=64, L=93 (text=77, face=16), INNER=3072.
// ---------------------------------------------------------------------------

#define C_DIM 768
#define B_DIM 2
#define N_DIM 1024
#define NC_DIM 1040   // 1024 + 16 face tokens
#define L_DIM 93
#define TEXT_LEN 77
#define INNER 3072

// Workspace offsets (floats). Phase-based reuse; total ~94.6 MB.
#define OFF_COMB  0u
#define OFF_Q     1600000u
#define OFF_K     3200000u
#define OFF_V     4800000u
#define OFF_ATTN  6400000u
#define OFF_HH    0u
#define OFF_T     1600000u
#define OFF_G     14200000u
#define OFF_X1    20500000u
#define OFF_X2    22080000u
#define OFF_Q2    0u
#define OFF_TEXT  1600000u
#define OFF_K2    1750000u
#define OFF_V2    1900000u
#define OFF_ATTN2 2100000u

// ---------------- block reduction (256 threads = 4 waves) -----------------
__device__ __forceinline__ float block_sum(float v, float* sh) {
#pragma unroll
  for (int o = 32; o > 0; o >>= 1) v += __shfl_down(v, o);
  int lane = threadIdx.x & 63, w = threadIdx.x >> 6;
  if (lane == 0) sh[w] = v;
  __syncthreads();
  float r = sh[0] + sh[1] + sh[2] + sh[3];
  __syncthreads();
  return r;
}

// ---------------- LN(x) and LN(face) -> comb ------------------------------
__global__ __launch_bounds__(256)
void ln_concat_kernel(const float* __restrict__ x, const float* __restrict__ enc,
                      const float* __restrict__ g, const float* __restrict__ b,
                      float* __restrict__ comb) {
  __shared__ float sh[4];
  int r = blockIdx.x;
  int bb = r / NC_DIM, i = r % NC_DIM;
  const float* src = (i < N_DIM)
      ? (x   + ((size_t)bb * N_DIM + i) * C_DIM)
      : (enc + ((size_t)bb * L_DIM + TEXT_LEN + (i - N_DIM)) * C_DIM);
  float v[3];
#pragma unroll
  for (int j = 0; j < 3; ++j) v[j] = src[threadIdx.x + j * 256];
  float mean = block_sum(v[0] + v[1] + v[2], sh) * (1.f / C_DIM);
  float sq = 0.f;
#pragma unroll
  for (int j = 0; j < 3; ++j) { float d = v[j] - mean; sq += d * d; }
  float var = block_sum(sq, sh) * (1.f / C_DIM);
  float rstd = rsqrtf(var + 1e-5f);
  float* dst = comb + (size_t)r * C_DIM;
#pragma unroll
  for (int j = 0; j < 3; ++j) {
    int c = threadIdx.x + j * 256;
    dst[c] = (v[j] - mean) * rstd * g[c] + b[c];
  }
}

// ---------------- double layernorm ----------------------------------------
__global__ __launch_bounds__(256)
void ln_double_kernel(const float* __restrict__ src,
                      const float* __restrict__ g1, const float* __restrict__ b1,
                      const float* __restrict__ g2, const float* __restrict__ b2,
                      float* __restrict__ out) {
  __shared__ float sh[4];
  const float* s = src + (size_t)blockIdx.x * C_DIM;
  float v[3];
#pragma unroll
  for (int j = 0; j < 3; ++j) v[j] = s[threadIdx.x + j * 256];
  float mean = block_sum(v[0] + v[1] + v[2], sh) * (1.f / C_DIM);
  float sq = 0.f;
#pragma unroll
  for (int j = 0; j < 3; ++j) { float d = v[j] - mean; sq += d * d; }
  float rstd = rsqrtf(block_sum(sq, sh) * (1.f / C_DIM) + 1e-5f);
  float y[3];
#pragma unroll
  for (int j = 0; j < 3; ++j) {
    int c = threadIdx.x + j * 256;
    y[j] = (v[j] - mean) * rstd * g1[c] + b1[c];
  }
  float mean2 = block_sum(y[0] + y[1] + y[2], sh) * (1.f / C_DIM);
  sq = 0.f;
#pragma unroll
  for (int j = 0; j < 3; ++j) { float d = y[j] - mean2; sq += d * d; }
  float rstd2 = rsqrtf(block_sum(sq, sh) * (1.f / C_DIM) + 1e-5f);
  float* dst = out + (size_t)blockIdx.x * C_DIM;
#pragma unroll
  for (int j = 0; j < 3; ++j) {
    int c = threadIdx.x + j * 256;
    dst[c] = (y[j] - mean2) * rstd2 * g2[c] + b2[c];
  }
}

// ---------------- generic tiled SGEMM with fused epilogue ------------------
#define BM 64
#define BN 64
#define BK 16
__global__ __launch_bounds__(256)
void gemm_kernel(const float* __restrict__ A, const float* __restrict__ W,
                 float* __restrict__ Out, int M, int N, int K,
                 const float* __restrict__ bias, const float* __restrict__ res,
                 const float* __restrict__ alphaPtr) {
  __shared__ float As[BK][BM + 4];
  __shared__ float Bs[BK][BN + 4];
  int t = threadIdx.x;
  int tx = t & 15, ty = t >> 4;
  int n0 = blockIdx.x * BN, m0 = blockIdx.y * BM;
  float c[4][4] = {};
  for (int k0 = 0; k0 < K; k0 += BK) {
#pragma unroll
    for (int l = 0; l < 4; ++l) {
      int e = t + l * 256;
      int m = e >> 4, kk = e & 15;
      int gm = m0 + m;
      As[kk][m] = (gm < M) ? A[(size_t)gm * K + k0 + kk] : 0.f;
    }
#pragma unroll
    for (int l = 0; l < 4; ++l) {
      int e = t + l * 256;
      int kk = e >> 6, n = e & 63;
      Bs[kk][n] = W[(size_t)(k0 + kk) * N + n0 + n];
    }
    __syncthreads();
#pragma unroll
    for (int kk = 0; kk < BK; ++kk) {
      float a[4], bvec[4];
#pragma unroll
      for (int j = 0; j < 4; ++j) a[j] = As[kk][ty * 4 + j];
#pragma unroll
      for (int i = 0; i < 4; ++i) bvec[i] = Bs[kk][tx * 4 + i];
#pragma unroll
      for (int j = 0; j < 4; ++j)
#pragma unroll
        for (int i = 0; i < 4; ++i) c[j][i] += a[j] * bvec[i];
    }
    __syncthreads();
  }
  float f = alphaPtr ? tanhf(alphaPtr[0]) : 1.0f;
#pragma unroll
  for (int j = 0; j < 4; ++j) {
    int gm = m0 + ty * 4 + j;
    if (gm >= M) continue;
#pragma unroll
    for (int i = 0; i < 4; ++i) {
      int gn = n0 + tx * 4 + i;
      float val = c[j][i];
      if (bias) val += bias[gn];
      if (res)  val = res[(size_t)gm * N + gn] + f * val;
      Out[(size_t)gm * N + gn] = val;
    }
  }
}

// ---------------- flash attention (register-tiled, R1) --------------------
// One block = one (b, h, 64-query tile). 256 threads, tx=t&15 (k/dv cols x4),
// ty=t>>4 (q rows x4). Per k-tile: S = Qt^T Kt via 4x4 register GEMM,
// shuffle softmax across the 16-lane row group, P->LDS (b128), PV GEMM.
// Qt/Kt stored [d][token] (pitch 68) so both GEMM operands read as float4.
__global__ __launch_bounds__(256)
void attn_kernel(const float* __restrict__ Q, const float* __restrict__ K,
                 const float* __restrict__ V, float* __restrict__ O,
                 int q_rows_per_b, int kv_rows_per_b, int Nk) {
  __shared__ float Qt[64][68];   // [d][q], pre-scaled by d^-0.5
  __shared__ float Kt[64][68];   // [d][k]
  __shared__ float Vs[64][68];   // [k][dv]
  __shared__ float Pt[64][68];   // [k][q]
  const float scale = 0.125f;    // 64^-0.5
  int t = threadIdx.x;
  int tx = t & 15, ty = t >> 4;
  int lane = t & 63, w = t >> 6;
  int b = blockIdx.z, h = blockIdx.y, q0 = blockIdx.x * 64;

  // ---- stage Q transposed: wave w handles q rows [w*16, w*16+16) ----
#pragma unroll
  for (int r4 = 0; r4 < 4; ++r4) {
    int qb = w * 16 + r4 * 4;
    float vals[4];
#pragma unroll
    for (int rr = 0; rr < 4; ++rr)
      vals[rr] = Q[((size_t)(b * q_rows_per_b + q0 + qb + rr)) * C_DIM + h * 64 + lane] * scale;
    *(float4*)&Qt[lane][qb] = make_float4(vals[0], vals[1], vals[2], vals[3]);
  }

  float m_i[4], l_i[4], acc[4][4];
#pragma unroll
  for (int j = 0; j < 4; ++j) {
    m_i[j] = -INFINITY; l_i[j] = 0.f;
#pragma unroll
    for (int i = 0; i < 4; ++i) acc[j][i] = 0.f;
  }

  int ntiles = (Nk + 63) >> 6;
  for (int kt = 0; kt < ntiles; ++kt) {
    int kbase_g = kt * 64;
    bool full = (kbase_g + 64 <= Nk);
    // ---- stage K transposed ----
#pragma unroll
    for (int r4 = 0; r4 < 4; ++r4) {
      int kb = w * 16 + r4 * 4;
      float vals[4];
#pragma unroll
      for (int rr = 0; rr < 4; ++rr) {
        int kj = kbase_g + kb + rr;
        vals[rr] = (kj < Nk)
            ? K[((size_t)(b * kv_rows_per_b + kj)) * C_DIM + h * 64 + lane] : 0.f;
      }
      *(float4*)&Kt[lane][kb] = make_float4(vals[0], vals[1], vals[2], vals[3]);
    }
    // ---- stage V natural [k][dv] ----
#pragma unroll
    for (int l4 = 0; l4 < 4; ++l4) {
      int r = l4 * 16 + (t >> 4);
      int c4 = (t & 15) * 4;
      int kj = kbase_g + r;
      float4 val = make_float4(0.f, 0.f, 0.f, 0.f);
      if (kj < Nk)
        val = *(const float4*)&V[((size_t)(b * kv_rows_per_b + kj)) * C_DIM + h * 64 + c4];
      *(float4*)&Vs[r][c4] = val;
    }
    __syncthreads();

    // ---- S = Q K^T (4x4 per thread) ----
    float cs[4][4] = {};
#pragma unroll 16
    for (int kk = 0; kk < 64; ++kk) {
      float4 a = *(const float4*)&Qt[kk][ty * 4];
      float4 bq = *(const float4*)&Kt[kk][tx * 4];
      float av[4] = {a.x, a.y, a.z, a.w};
      float bv[4] = {bq.x, bq.y, bq.z, bq.w};
#pragma unroll
      for (int j = 0; j < 4; ++j)
#pragma unroll
        for (int i = 0; i < 4; ++i) cs[j][i] += av[j] * bv[i];
    }
    if (!full) {
#pragma unroll
      for (int i = 0; i < 4; ++i)
        if (kbase_g + tx * 4 + i >= Nk) {
#pragma unroll
          for (int j = 0; j < 4; ++j) cs[j][i] = -INFINITY;
        }
    }

    // ---- online softmax: row j lives on 16 consecutive lanes (tx) ----
#pragma unroll
    for (int j = 0; j < 4; ++j) {
      float rmax = fmaxf(fmaxf(cs[j][0], cs[j][1]), fmaxf(cs[j][2], cs[j][3]));
#pragma unroll
      for (int o = 1; o < 16; o <<= 1) rmax = fmaxf(rmax, __shfl_xor(rmax, o));
      float mnew = fmaxf(m_i[j], rmax);
      float alpha = __expf(m_i[j] - mnew);
      float psum = 0.f;
#pragma unroll
      for (int i = 0; i < 4; ++i) {
        float p = __expf(cs[j][i] - mnew);
        cs[j][i] = p; psum += p;
      }
#pragma unroll
      for (int o = 1; o < 16; o <<= 1) psum += __shfl_xor(psum, o);
      l_i[j] = l_i[j] * alpha + psum;
      m_i[j] = mnew;
#pragma unroll
      for (int i = 0; i < 4; ++i) acc[j][i] *= alpha;
    }

    // ---- write P transposed [k][q] via b128 ----
#pragma unroll
    for (int i = 0; i < 4; ++i)
      *(float4*)&Pt[tx * 4 + i][ty * 4] = make_float4(cs[0][i], cs[1][i], cs[2][i], cs[3][i]);
    __syncthreads();

    // ---- O += P V (4x4 per thread) ----
#pragma unroll 16
    for (int kk = 0; kk < 64; ++kk) {
      float4 p = *(const float4*)&Pt[kk][ty * 4];
      float4 vv = *(const float4*)&Vs[kk][tx * 4];
      float pv[4] = {p.x, p.y, p.z, p.w};
      float vvv[4] = {vv.x, vv.y, vv.z, vv.w};
#pragma unroll
      for (int j = 0; j < 4; ++j)
#pragma unroll
        for (int i = 0; i < 4; ++i) acc[j][i] += pv[j] * vvv[i];
    }
    __syncthreads();   // protect Kt/Vs/Pt before next tile's staging
  }

  // ---- epilogue ----
#pragma unroll
  for (int j = 0; j < 4; ++j) {
    float inv = 1.f / l_i[j];
    int row = b * N_DIM + q0 + ty * 4 + j;
    float4 o = make_float4(acc[j][0] * inv, acc[j][1] * inv, acc[j][2] * inv, acc[j][3] * inv);
    *(float4*)&O[(size_t)row * C_DIM + h * 64 + tx * 4] = o;
  }
}

// ---------------- GEGLU ----------------------------------------------------
__global__ __launch_bounds__(256)
void geglu_kernel(const float* __restrict__ tbuf, float* __restrict__ g) {
  int idx = blockIdx.x * 256 + threadIdx.x;
  int r = idx / INNER, c = idx % INNER;
  float a = tbuf[(size_t)r * (2 * INNER) + c];
  float x = tbuf[(size_t)r * (2 * INNER) + INNER + c];
  float ge = 0.5f * x * (1.f + erff(x * 0.70710678118654752f));
  g[idx] = a * ge;
}

// ---------------- text gather ----------------------------------------------
__global__ __launch_bounds__(256)
void gather_text_kernel(const float* __restrict__ enc, float* __restrict__ out) {
  int r = blockIdx.x;
  int bb = r / TEXT_LEN, j = r % TEXT_LEN;
  const float* src = enc + ((size_t)bb * L_DIM + j) * C_DIM;
  float* dst = out + (size_t)r * C_DIM;
#pragma unroll
  for (int l = 0; l < 3; ++l) {
    int c = threadIdx.x + l * 256;
    dst[c] = src[c];
  }
}

// ---------------------------------------------------------------------------
extern "C" void kernel_launch(void* const* d_in, const int* in_sizes, int n_in,
                              void* d_out, int out_size, void* d_ws, size_t ws_size,
                              hipStream_t stream) {
  const float* x        = (const float*)d_in[0];
  const float* enc      = (const float*)d_in[1];
  const float* ln1_g    = (const float*)d_in[2];
  const float* ln1_b    = (const float*)d_in[3];
  const float* ln2_g    = (const float*)d_in[4];
  const float* ln2_b    = (const float*)d_in[5];
  const float* sa_wq    = (const float*)d_in[6];
  const float* sa_wk    = (const float*)d_in[7];
  const float* sa_wv    = (const float*)d_in[8];
  const float* sa_wo    = (const float*)d_in[9];
  const float* sa_wo_b  = (const float*)d_in[10];
  const float* ff_ln_g  = (const float*)d_in[11];
  const float* ff_ln_b  = (const float*)d_in[12];
  const float* ff_w1    = (const float*)d_in[13];
  const float* ff_w2    = (const float*)d_in[14];
  const float* a_attn   = (const float*)d_in[15];
  const float* a_dense  = (const float*)d_in[16];
  const float* ca_wq    = (const float*)d_in[17];
  const float* ca_wk    = (const float*)d_in[18];
  const float* ca_wv    = (const float*)d_in[19];
  const float* ca_wo    = (const float*)d_in[20];
  const float* ca_wo_b  = (const float*)d_in[21];

  float* ws = (float*)d_ws;
  float* comb  = ws + OFF_COMB;
  float* q     = ws + OFF_Q;
  float* k     = ws + OFF_K;
  float* v     = ws + OFF_V;
  float* attn  = ws + OFF_ATTN;
  float* hh    = ws + OFF_HH;
  float* tbuf  = ws + OFF_T;
  float* g     = ws + OFF_G;
  float* x1    = ws + OFF_X1;
  float* x2    = ws + OFF_X2;
  float* q2    = ws + OFF_Q2;
  float* text  = ws + OFF_TEXT;
  float* k2    = ws + OFF_K2;
  float* v2    = ws + OFF_V2;
  float* attn2 = ws + OFF_ATTN2;
  float* out   = (float*)d_out;

  const int Mc = B_DIM * NC_DIM;   // 2080
  const int Mx = B_DIM * N_DIM;    // 2048
  const int Mt = B_DIM * TEXT_LEN; // 154

  auto gemm_grid = [](int M, int N) { return dim3(N / BN, (M + BM - 1) / BM); };

  ln_concat_kernel<<<Mc, 256, 0, stream>>>(x, enc, ln1_g, ln1_b, comb);
  gemm_kernel<<<gemm_grid(Mc, C_DIM), 256, 0, stream>>>(comb, sa_wq, q, Mc, C_DIM, C_DIM, nullptr, nullptr, nullptr);
  gemm_kernel<<<gemm_grid(Mc, C_DIM), 256, 0, stream>>>(comb, sa_wk, k, Mc, C_DIM, C_DIM, nullptr, nullptr, nullptr);
  gemm_kernel<<<gemm_grid(Mc, C_DIM), 256, 0, stream>>>(comb, sa_wv, v, Mc, C_DIM, C_DIM, nullptr, nullptr, nullptr);
  attn_kernel<<<dim3(N_DIM / 64, 12, B_DIM), 256, 0, stream>>>(q, k, v, attn, NC_DIM, NC_DIM, NC_DIM);
  gemm_kernel<<<gemm_grid(Mx, C_DIM), 256, 0, stream>>>(attn, sa_wo, x1, Mx, C_DIM, C_DIM, sa_wo_b, x, a_attn);
  ln_double_kernel<<<Mx, 256, 0, stream>>>(x1, ln2_g, ln2_b, ff_ln_g, ff_ln_b, hh);
  gemm_kernel<<<gemm_grid(Mx, 2 * INNER), 256, 0, stream>>>(hh, ff_w1, tbuf, Mx, 2 * INNER, C_DIM, nullptr, nullptr, nullptr);
  geglu_kernel<<<(Mx * INNER) / 256, 256, 0, stream>>>(tbuf, g);
  gemm_kernel<<<gemm_grid(Mx, C_DIM), 256, 0, stream>>>(g, ff_w2, x2, Mx, C_DIM, INNER, nullptr, x1, a_dense);
  gather_text_kernel<<<Mt, 256, 0, stream>>>(enc, text);
  gemm_kernel<<<gemm_grid(Mx, C_DIM), 256, 0, stream>>>(x2, ca_wq, q2, Mx, C_DIM, C_DIM, nullptr, nullptr, nullptr);
  gemm_kernel<<<gemm_grid(Mt, C_DIM), 256, 0, stream>>>(text, ca_wk, k2, Mt, C_DIM, C_DIM, nullptr, nullptr, nullptr);
  gemm_kernel<<<gemm_grid(Mt, C_DIM), 256, 0, stream>>>(text, ca_wv, v2, Mt, C_DIM, C_DIM, nullptr, nullptr, nullptr);
  attn_kernel<<<dim3(N_DIM / 64, 12, B_DIM), 256, 0, stream>>>(q2, k2, v2, attn2, N_DIM, TEXT_LEN, TEXT_LEN);
  gemm_kernel<<<gemm_grid(Mx, C_DIM), 256, 0, stream>>>(attn2, ca_wo, out, Mx, C_DIM, C_DIM, ca_wo_b, x2, nullptr);
}

// Round 3
// 918.896 us; speedup vs baseline: 2.7920x; 1.8748x over previous
//
#include <hip/hip_runtime.h>
#include <hip/hip_bf16.h>
#include <math.h>

// ---------------------------------------------------------------------------
// FaceAttnProcessor forward. R2: all weight GEMMs -> bf16 MFMA (m97-style
// 128x128 tile, 16x16x32 MFMA, global_load_lds). Attention = R1 register-
// tiled fp32 VALU but bf16 I/O. Weights cast+transposed to bf16 per launch.
// B=2, N=1024, C=768, H=12, d=64, L=93 (text=77, face=16), INNER=3072.
// ---------------------------------------------------------------------------

#define C_DIM 768
#define B_DIM 2
#define N_DIM 1024
#define NC_DIM 1040
#define L_DIM 93
#define TEXT_LEN 77
#define INNER 3072

typedef unsigned short ushort_t;
typedef __bf16 bf16x8 __attribute__((ext_vector_type(8)));
typedef float f32x4 __attribute__((ext_vector_type(4)));

__device__ __forceinline__ ushort_t f2b(float f) {
  __hip_bfloat16 h = __float2bfloat16(f);
  return *(ushort_t*)&h;
}
__device__ __forceinline__ float b2f(ushort_t u) {
  __hip_bfloat16 h = *(__hip_bfloat16*)&u;
  return __bfloat162float(h);
}

__device__ __forceinline__ void g2lds16(const void* g, void* l) {
  __builtin_amdgcn_global_load_lds(
      (const __attribute__((address_space(1))) unsigned int*)g,
      (__attribute__((address_space(3))) unsigned int*)l, 16, 0, 0);
}

// ---------------- workspace map (byte offsets) ----------------------------
#define WX1    0u           // fp32 x1 (2048*768)
#define WX2    6291456u     // fp32 x2
#define WQKV   12582912u    // u16 qkv_b [2080][2304]; later q2b[2048][768]+kv2b[154][1536]
#define WBB1   22167552u    // u16 comb_b / attn_b / tbuf_b (25.17 MB)
#define WG     47333376u    // u16 g_b [2048][3072]
#define WS1    59916288u    // u16 hh / x2b [2048][768]
#define WTEXT  63062016u    // u16 text_b [154][768]
#define WATT2  63298560u    // u16 attn2b [2048][768]
#define WWQKV  66444288u    // u16 wqkv_t [2304][768]
#define WWO    69983232u    // u16 wo_t   [768][768]
#define WW1    71162880u    // u16 w1_t   [6144][768]
#define WW2    80600064u    // u16 w2_t   [768][3072]
#define WCAWQ  85318656u    // u16 cawq_t [768][768]
#define WCAKV  86498304u    // u16 cakv_t [1536][768]
#define WCAWO  88857600u    // u16 cawo_t [768][768]

// ---------------- block reduction (256 threads = 4 waves) -----------------
__device__ __forceinline__ float block_sum(float v, float* sh) {
#pragma unroll
  for (int o = 32; o > 0; o >>= 1) v += __shfl_down(v, o);
  int lane = threadIdx.x & 63, w = threadIdx.x >> 6;
  if (lane == 0) sh[w] = v;
  __syncthreads();
  float r = sh[0] + sh[1] + sh[2] + sh[3];
  __syncthreads();
  return r;
}

// ---------------- weight cast + transpose: fp32 [K][N] -> bf16 [N][K] -----
__global__ __launch_bounds__(256)
void wtrans_kernel(const float* __restrict__ in, ushort_t* __restrict__ out,
                   int K, int N) {
  __shared__ float tile[64][65];
  int k0 = blockIdx.y * 64, n0 = blockIdx.x * 64;
  int t = threadIdx.x;
#pragma unroll
  for (int p = 0; p < 16; ++p) {
    int idx = t + p * 256;   // 4096 elems / 256 threads = 16
    if (p < 16) {
      int r = idx >> 6, c = idx & 63;
      if (p < 16 && idx < 4096) tile[r][c] = in[(size_t)(k0 + r) * N + n0 + c];
    }
    if (p == 15) break;
  }
  __syncthreads();
#pragma unroll
  for (int p = 0; p < 16; ++p) {
    int idx = t + p * 256;
    int r = idx >> 6, c = idx & 63;
    out[(size_t)(n0 + r) * K + k0 + c] = f2b(tile[c][r]);
  }
}

// ---------------- LN(x) and LN(face) -> comb (bf16) -----------------------
__global__ __launch_bounds__(256)
void ln_concat_kernel(const float* __restrict__ x, const float* __restrict__ enc,
                      const float* __restrict__ g, const float* __restrict__ b,
                      ushort_t* __restrict__ comb) {
  __shared__ float sh[4];
  int r = blockIdx.x;
  int bb = r / NC_DIM, i = r % NC_DIM;
  const float* src = (i < N_DIM)
      ? (x   + ((size_t)bb * N_DIM + i) * C_DIM)
      : (enc + ((size_t)bb * L_DIM + TEXT_LEN + (i - N_DIM)) * C_DIM);
  float v[3];
#pragma unroll
  for (int j = 0; j < 3; ++j) v[j] = src[threadIdx.x + j * 256];
  float mean = block_sum(v[0] + v[1] + v[2], sh) * (1.f / C_DIM);
  float sq = 0.f;
#pragma unroll
  for (int j = 0; j < 3; ++j) { float d = v[j] - mean; sq += d * d; }
  float rstd = rsqrtf(block_sum(sq, sh) * (1.f / C_DIM) + 1e-5f);
  ushort_t* dst = comb + (size_t)r * C_DIM;
#pragma unroll
  for (int j = 0; j < 3; ++j) {
    int c = threadIdx.x + j * 256;
    dst[c] = f2b((v[j] - mean) * rstd * g[c] + b[c]);
  }
}

// ---------------- double layernorm: fp32 in -> bf16 out -------------------
__global__ __launch_bounds__(256)
void ln_double_kernel(const float* __restrict__ src,
                      const float* __restrict__ g1, const float* __restrict__ b1,
                      const float* __restrict__ g2, const float* __restrict__ b2,
                      ushort_t* __restrict__ out) {
  __shared__ float sh[4];
  const float* s = src + (size_t)blockIdx.x * C_DIM;
  float v[3];
#pragma unroll
  for (int j = 0; j < 3; ++j) v[j] = s[threadIdx.x + j * 256];
  float mean = block_sum(v[0] + v[1] + v[2], sh) * (1.f / C_DIM);
  float sq = 0.f;
#pragma unroll
  for (int j = 0; j < 3; ++j) { float d = v[j] - mean; sq += d * d; }
  float rstd = rsqrtf(block_sum(sq, sh) * (1.f / C_DIM) + 1e-5f);
  float y[3];
#pragma unroll
  for (int j = 0; j < 3; ++j) {
    int c = threadIdx.x + j * 256;
    y[j] = (v[j] - mean) * rstd * g1[c] + b1[c];
  }
  float mean2 = block_sum(y[0] + y[1] + y[2], sh) * (1.f / C_DIM);
  sq = 0.f;
#pragma unroll
  for (int j = 0; j < 3; ++j) { float d = y[j] - mean2; sq += d * d; }
  float rstd2 = rsqrtf(block_sum(sq, sh) * (1.f / C_DIM) + 1e-5f);
  ushort_t* dst = out + (size_t)blockIdx.x * C_DIM;
#pragma unroll
  for (int j = 0; j < 3; ++j) {
    int c = threadIdx.x + j * 256;
    dst[c] = f2b((y[j] - mean2) * rstd2 * g2[c] + b2[c]);
  }
}

// ---------------- bf16 MFMA GEMM (m97 structure) ---------------------------
// C[M,N] = A[M,K] @ Bt[N,K]^T, fp32 accum. 128x128 tile, 4 waves (2x2),
// each wave 64x64 = 4x4 MFMA subtiles of 16x16x32. BK=32.
// Epilogue: +bias[n]; res: val = res[m,n] + tanh(*alphaPtr)*val;
// writes Out (fp32) and/or Ob (bf16).
__global__ __launch_bounds__(256)
void gemm_bf16(const ushort_t* __restrict__ A, const ushort_t* __restrict__ Bt,
               float* __restrict__ Out, ushort_t* __restrict__ Ob,
               int M, int N, int K,
               const float* __restrict__ bias, const float* __restrict__ res,
               const float* __restrict__ alphaPtr) {
  __shared__ ushort_t sA[128 * 32];   // [m][k] rows of 32 bf16 (64 B)
  __shared__ ushort_t sB[128 * 32];   // [n][k]
  int t = threadIdx.x;
  int w = t >> 6, ln = t & 63;
  int m0 = blockIdx.y * 128, n0 = blockIdx.x * 128;
  int wm = (w >> 1) * 64, wn = (w & 1) * 64;
  int lr = ln & 15;        // row/col within 16x16
  int lq = ln >> 4;        // quad -> k-offset lq*8, C-row lq*4
  int seg_r = ln >> 2;     // staging: row within 16-row segment
  int seg_c = (ln & 3) * 8;

  f32x4 acc[4][4];
#pragma unroll
  for (int mi = 0; mi < 4; ++mi)
#pragma unroll
    for (int ni = 0; ni < 4; ++ni) acc[mi][ni] = (f32x4){0.f, 0.f, 0.f, 0.f};

  for (int k0 = 0; k0 < K; k0 += 32) {
#pragma unroll
    for (int l = 0; l < 2; ++l) {
      int s = w * 2 + l;                    // segment 0..7 (16 rows each)
      int arow = m0 + s * 16 + seg_r;
      arow = arow < M ? arow : M - 1;       // clamp (epilogue guards stores)
      g2lds16(A + (size_t)arow * K + k0 + seg_c, sA + s * 512);
      int nrow = n0 + s * 16 + seg_r;       // N is always a multiple of 128
      g2lds16(Bt + (size_t)nrow * K + k0 + seg_c, sB + s * 512);
    }
    __syncthreads();
    bf16x8 af[4], bf[4];
#pragma unroll
    for (int mi = 0; mi < 4; ++mi)
      af[mi] = *(const bf16x8*)&sA[(wm + mi * 16 + lr) * 32 + lq * 8];
#pragma unroll
    for (int ni = 0; ni < 4; ++ni)
      bf[ni] = *(const bf16x8*)&sB[(wn + ni * 16 + lr) * 32 + lq * 8];
#pragma unroll
    for (int mi = 0; mi < 4; ++mi)
#pragma unroll
      for (int ni = 0; ni < 4; ++ni)
        acc[mi][ni] = __builtin_amdgcn_mfma_f32_16x16x32_bf16(
            af[mi], bf[ni], acc[mi][ni], 0, 0, 0);
    __syncthreads();
  }

  float f = alphaPtr ? tanhf(alphaPtr[0]) : 1.0f;
#pragma unroll
  for (int mi = 0; mi < 4; ++mi) {
#pragma unroll
    for (int ni = 0; ni < 4; ++ni) {
      int col = n0 + wn + ni * 16 + lr;
      float bv = bias ? bias[col] : 0.f;
#pragma unroll
      for (int r = 0; r < 4; ++r) {
        int row = m0 + wm + mi * 16 + lq * 4 + r;
        if (row < M) {
          float val = acc[mi][ni][r] + bv;
          if (res) val = res[(size_t)row * N + col] + f * val;
          if (Out) Out[(size_t)row * N + col] = val;
          if (Ob)  Ob[(size_t)row * N + col] = f2b(val);
        }
      }
    }
  }
}

// ---------------- flash attention (register-tiled, bf16 I/O) --------------
// Q/K/V bf16 with row strides (strided views into fused qkv buffers).
// O bf16 [B*1024][768].
__global__ __launch_bounds__(256)
void attn_kernel(const ushort_t* __restrict__ Q, const ushort_t* __restrict__ K,
                 const ushort_t* __restrict__ V, ushort_t* __restrict__ O,
                 int q_rows_per_b, int kv_rows_per_b, int Nk,
                 int qstride, int kvstride) {
  __shared__ float Qt[64][68];   // [d][q], pre-scaled
  __shared__ float Kt[64][68];   // [d][k]
  __shared__ float Vs[64][68];   // [k][dv]
  __shared__ float Pt[64][68];   // [k][q]
  const float scale = 0.125f;
  int t = threadIdx.x;
  int tx = t & 15, ty = t >> 4;
  int lane = t & 63, w = t >> 6;
  int b = blockIdx.z, h = blockIdx.y, q0 = blockIdx.x * 64;

#pragma unroll
  for (int r4 = 0; r4 < 4; ++r4) {
    int qb = w * 16 + r4 * 4;
    float vals[4];
#pragma unroll
    for (int rr = 0; rr < 4; ++rr)
      vals[rr] = b2f(Q[((size_t)(b * q_rows_per_b + q0 + qb + rr)) * qstride + h * 64 + lane]) * scale;
    *(float4*)&Qt[lane][qb] = make_float4(vals[0], vals[1], vals[2], vals[3]);
  }

  float m_i[4], l_i[4], acc[4][4];
#pragma unroll
  for (int j = 0; j < 4; ++j) {
    m_i[j] = -INFINITY; l_i[j] = 0.f;
#pragma unroll
    for (int i = 0; i < 4; ++i) acc[j][i] = 0.f;
  }

  int ntiles = (Nk + 63) >> 6;
  for (int kt = 0; kt < ntiles; ++kt) {
    int kbase_g = kt * 64;
    bool full = (kbase_g + 64 <= Nk);
#pragma unroll
    for (int r4 = 0; r4 < 4; ++r4) {
      int kb = w * 16 + r4 * 4;
      float vals[4];
#pragma unroll
      for (int rr = 0; rr < 4; ++rr) {
        int kj = kbase_g + kb + rr;
        vals[rr] = (kj < Nk)
            ? b2f(K[((size_t)(b * kv_rows_per_b + kj)) * kvstride + h * 64 + lane]) : 0.f;
      }
      *(float4*)&Kt[lane][kb] = make_float4(vals[0], vals[1], vals[2], vals[3]);
    }
#pragma unroll
    for (int l4 = 0; l4 < 4; ++l4) {
      int r = l4 * 16 + (t >> 4);
      int c4 = (t & 15) * 4;
      int kj = kbase_g + r;
      float4 val = make_float4(0.f, 0.f, 0.f, 0.f);
      if (kj < Nk) {
        ushort4 u = *(const ushort4*)&V[((size_t)(b * kv_rows_per_b + kj)) * kvstride + h * 64 + c4];
        val = make_float4(b2f(u.x), b2f(u.y), b2f(u.z), b2f(u.w));
      }
      *(float4*)&Vs[r][c4] = val;
    }
    __syncthreads();

    float cs[4][4] = {};
#pragma unroll 16
    for (int kk = 0; kk < 64; ++kk) {
      float4 a = *(const float4*)&Qt[kk][ty * 4];
      float4 bq = *(const float4*)&Kt[kk][tx * 4];
      float av[4] = {a.x, a.y, a.z, a.w};
      float bv[4] = {bq.x, bq.y, bq.z, bq.w};
#pragma unroll
      for (int j = 0; j < 4; ++j)
#pragma unroll
        for (int i = 0; i < 4; ++i) cs[j][i] += av[j] * bv[i];
    }
    if (!full) {
#pragma unroll
      for (int i = 0; i < 4; ++i)
        if (kbase_g + tx * 4 + i >= Nk) {
#pragma unroll
          for (int j = 0; j < 4; ++j) cs[j][i] = -INFINITY;
        }
    }

#pragma unroll
    for (int j = 0; j < 4; ++j) {
      float rmax = fmaxf(fmaxf(cs[j][0], cs[j][1]), fmaxf(cs[j][2], cs[j][3]));
#pragma unroll
      for (int o = 1; o < 16; o <<= 1) rmax = fmaxf(rmax, __shfl_xor(rmax, o));
      float mnew = fmaxf(m_i[j], rmax);
      float alpha = __expf(m_i[j] - mnew);
      float psum = 0.f;
#pragma unroll
      for (int i = 0; i < 4; ++i) {
        float p = __expf(cs[j][i] - mnew);
        cs[j][i] = p; psum += p;
      }
#pragma unroll
      for (int o = 1; o < 16; o <<= 1) psum += __shfl_xor(psum, o);
      l_i[j] = l_i[j] * alpha + psum;
      m_i[j] = mnew;
#pragma unroll
      for (int i = 0; i < 4; ++i) acc[j][i] *= alpha;
    }

#pragma unroll
    for (int i = 0; i < 4; ++i)
      *(float4*)&Pt[tx * 4 + i][ty * 4] = make_float4(cs[0][i], cs[1][i], cs[2][i], cs[3][i]);
    __syncthreads();

#pragma unroll 16
    for (int kk = 0; kk < 64; ++kk) {
      float4 p = *(const float4*)&Pt[kk][ty * 4];
      float4 vv = *(const float4*)&Vs[kk][tx * 4];
      float pv[4] = {p.x, p.y, p.z, p.w};
      float vvv[4] = {vv.x, vv.y, vv.z, vv.w};
#pragma unroll
      for (int j = 0; j < 4; ++j)
#pragma unroll
        for (int i = 0; i < 4; ++i) acc[j][i] += pv[j] * vvv[i];
    }
    __syncthreads();
  }

#pragma unroll
  for (int j = 0; j < 4; ++j) {
    float inv = 1.f / l_i[j];
    int row = b * N_DIM + q0 + ty * 4 + j;
    ushort4 o;
    o.x = f2b(acc[j][0] * inv); o.y = f2b(acc[j][1] * inv);
    o.z = f2b(acc[j][2] * inv); o.w = f2b(acc[j][3] * inv);
    *(ushort4*)&O[(size_t)row * C_DIM + h * 64 + tx * 4] = o;
  }
}

// ---------------- GEGLU: bf16 in [2048][6144] -> bf16 out [2048][3072] ----
__global__ __launch_bounds__(256)
void geglu_kernel(const ushort_t* __restrict__ tbuf, ushort_t* __restrict__ g) {
  int idx = blockIdx.x * 256 + threadIdx.x;
  int r = idx / INNER, c = idx % INNER;
  float a = b2f(tbuf[(size_t)r * (2 * INNER) + c]);
  float x = b2f(tbuf[(size_t)r * (2 * INNER) + INNER + c]);
  float ge = 0.5f * x * (1.f + erff(x * 0.70710678118654752f));
  g[idx] = f2b(a * ge);
}

// ---------------- text gather: fp32 -> bf16 compact (154,768) -------------
__global__ __launch_bounds__(256)
void gather_text_kernel(const float* __restrict__ enc, ushort_t* __restrict__ out) {
  int r = blockIdx.x;
  int bb = r / TEXT_LEN, j = r % TEXT_LEN;
  const float* src = enc + ((size_t)bb * L_DIM + j) * C_DIM;
  ushort_t* dst = out + (size_t)r * C_DIM;
#pragma unroll
  for (int l = 0; l < 3; ++l) {
    int c = threadIdx.x + l * 256;
    dst[c] = f2b(src[c]);
  }
}

// ---------------------------------------------------------------------------
extern "C" void kernel_launch(void* const* d_in, const int* in_sizes, int n_in,
                              void* d_out, int out_size, void* d_ws, size_t ws_size,
                              hipStream_t stream) {
  const float* x        = (const float*)d_in[0];
  const float* enc      = (const float*)d_in[1];
  const float* ln1_g    = (const float*)d_in[2];
  const float* ln1_b    = (const float*)d_in[3];
  const float* ln2_g    = (const float*)d_in[4];
  const float* ln2_b    = (const float*)d_in[5];
  const float* sa_wq    = (const float*)d_in[6];
  const float* sa_wk    = (const float*)d_in[7];
  const float* sa_wv    = (const float*)d_in[8];
  const float* sa_wo    = (const float*)d_in[9];
  const float* sa_wo_b  = (const float*)d_in[10];
  const float* ff_ln_g  = (const float*)d_in[11];
  const float* ff_ln_b  = (const float*)d_in[12];
  const float* ff_w1    = (const float*)d_in[13];
  const float* ff_w2    = (const float*)d_in[14];
  const float* a_attn   = (const float*)d_in[15];
  const float* a_dense  = (const float*)d_in[16];
  const float* ca_wq    = (const float*)d_in[17];
  const float* ca_wk    = (const float*)d_in[18];
  const float* ca_wv    = (const float*)d_in[19];
  const float* ca_wo    = (const float*)d_in[20];
  const float* ca_wo_b  = (const float*)d_in[21];

  char* ws = (char*)d_ws;
  float*    x1     = (float*)(ws + WX1);
  float*    x2     = (float*)(ws + WX2);
  ushort_t* qkv_b  = (ushort_t*)(ws + WQKV);
  ushort_t* q2b    = (ushort_t*)(ws + WQKV);
  ushort_t* kv2b   = (ushort_t*)(ws + WQKV + 3145728u);
  ushort_t* comb_b = (ushort_t*)(ws + WBB1);
  ushort_t* attn_b = (ushort_t*)(ws + WBB1);
  ushort_t* tbuf_b = (ushort_t*)(ws + WBB1);
  ushort_t* g_b    = (ushort_t*)(ws + WG);
  ushort_t* hh     = (ushort_t*)(ws + WS1);
  ushort_t* x2b    = (ushort_t*)(ws + WS1);
  ushort_t* text_b = (ushort_t*)(ws + WTEXT);
  ushort_t* attn2b = (ushort_t*)(ws + WATT2);
  ushort_t* wqkv_t = (ushort_t*)(ws + WWQKV);
  ushort_t* wo_t   = (ushort_t*)(ws + WWO);
  ushort_t* w1_t   = (ushort_t*)(ws + WW1);
  ushort_t* w2_t   = (ushort_t*)(ws + WW2);
  ushort_t* cawq_t = (ushort_t*)(ws + WCAWQ);
  ushort_t* cakv_t = (ushort_t*)(ws + WCAKV);
  ushort_t* cawo_t = (ushort_t*)(ws + WCAWO);
  float* out = (float*)d_out;

  const int Mc = B_DIM * NC_DIM;   // 2080
  const int Mx = B_DIM * N_DIM;    // 2048
  const int Mt = B_DIM * TEXT_LEN; // 154

  // ---- weight casts + transposes (fp32 [K][N] -> bf16 [N][K]) ----
  dim3 tg(12, 12);   // 768x768
  wtrans_kernel<<<tg, 256, 0, stream>>>(sa_wq, wqkv_t + 0 * 589824, C_DIM, C_DIM);
  wtrans_kernel<<<tg, 256, 0, stream>>>(sa_wk, wqkv_t + 1 * 589824, C_DIM, C_DIM);
  wtrans_kernel<<<tg, 256, 0, stream>>>(sa_wv, wqkv_t + 2 * 589824, C_DIM, C_DIM);
  wtrans_kernel<<<tg, 256, 0, stream>>>(sa_wo, wo_t, C_DIM, C_DIM);
  wtrans_kernel<<<dim3(96, 12), 256, 0, stream>>>(ff_w1, w1_t, C_DIM, 2 * INNER);
  wtrans_kernel<<<dim3(12, 48), 256, 0, stream>>>(ff_w2, w2_t, INNER, C_DIM);
  wtrans_kernel<<<tg, 256, 0, stream>>>(ca_wq, cawq_t, C_DIM, C_DIM);
  wtrans_kernel<<<tg, 256, 0, stream>>>(ca_wk, cakv_t + 0 * 589824, C_DIM, C_DIM);
  wtrans_kernel<<<tg, 256, 0, stream>>>(ca_wv, cakv_t + 1 * 589824, C_DIM, C_DIM);
  wtrans_kernel<<<tg, 256, 0, stream>>>(ca_wo, cawo_t, C_DIM, C_DIM);

  // ---- pipeline ----
  ln_concat_kernel<<<Mc, 256, 0, stream>>>(x, enc, ln1_g, ln1_b, comb_b);
  // fused qkv: [2080,2304] = comb @ [wq|wk|wv]
  gemm_bf16<<<dim3(2304 / 128, (Mc + 127) / 128), 256, 0, stream>>>(
      comb_b, wqkv_t, nullptr, qkv_b, Mc, 2304, C_DIM, nullptr, nullptr, nullptr);
  attn_kernel<<<dim3(N_DIM / 64, 12, B_DIM), 256, 0, stream>>>(
      qkv_b + 0, qkv_b + 768, qkv_b + 1536, attn_b, NC_DIM, NC_DIM, NC_DIM, 2304, 2304);
  gemm_bf16<<<dim3(768 / 128, Mx / 128), 256, 0, stream>>>(
      attn_b, wo_t, x1, nullptr, Mx, C_DIM, C_DIM, sa_wo_b, x, a_attn);
  ln_double_kernel<<<Mx, 256, 0, stream>>>(x1, ln2_g, ln2_b, ff_ln_g, ff_ln_b, hh);
  gemm_bf16<<<dim3(6144 / 128, Mx / 128), 256, 0, stream>>>(
      hh, w1_t, nullptr, tbuf_b, Mx, 2 * INNER, C_DIM, nullptr, nullptr, nullptr);
  geglu_kernel<<<(Mx * INNER) / 256, 256, 0, stream>>>(tbuf_b, g_b);
  gemm_bf16<<<dim3(768 / 128, Mx / 128), 256, 0, stream>>>(
      g_b, w2_t, x2, x2b, Mx, C_DIM, INNER, nullptr, x1, a_dense);
  gather_text_kernel<<<Mt, 256, 0, stream>>>(enc, text_b);
  gemm_bf16<<<dim3(768 / 128, Mx / 128), 256, 0, stream>>>(
      x2b, cawq_t, nullptr, q2b, Mx, C_DIM, C_DIM, nullptr, nullptr, nullptr);
  gemm_bf16<<<dim3(1536 / 128, (Mt + 127) / 128), 256, 0, stream>>>(
      text_b, cakv_t, nullptr, kv2b, Mt, 1536, C_DIM, nullptr, nullptr, nullptr);
  attn_kernel<<<dim3(N_DIM / 64, 12, B_DIM), 256, 0, stream>>>(
      q2b, kv2b + 0, kv2b + 768, attn2b, N_DIM, TEXT_LEN, TEXT_LEN, 768, 1536);
  gemm_bf16<<<dim3(768 / 128, Mx / 128), 256, 0, stream>>>(
      attn2b, cawo_t, out, nullptr, Mx, C_DIM, C_DIM, ca_wo_b, x2, nullptr);
}

// Round 4
// 532.937 us; speedup vs baseline: 4.8140x; 1.7242x over previous
//
#include <hip/hip_runtime.h>
#include <hip/hip_bf16.h>
#include <math.h>

// ---------------------------------------------------------------------------
// FaceAttnProcessor forward. R3: attention -> MFMA (16x16x32 bf16 QK^T and PV,
// online softmax via shfl_xor, P through per-wave LDS, V pre-transposed).
// GEMMs = R2 m97-style bf16 MFMA. Weights cast+transposed per launch.
// B=2, N=1024, C=768, H=12, d=64, L=93 (text=77, face=16), INNER=3072.
// ---------------------------------------------------------------------------

#define C_DIM 768
#define B_DIM 2
#define N_DIM 1024
#define NC_DIM 1040
#define L_DIM 93
#define TEXT_LEN 77
#define INNER 3072

typedef unsigned short ushort_t;
typedef __bf16 bf16x8 __attribute__((ext_vector_type(8)));
typedef float f32x4 __attribute__((ext_vector_type(4)));

__device__ __forceinline__ ushort_t f2b(float f) {
  __hip_bfloat16 h = __float2bfloat16(f);
  return *(ushort_t*)&h;
}
__device__ __forceinline__ float b2f(ushort_t u) {
  __hip_bfloat16 h = *(__hip_bfloat16*)&u;
  return __bfloat162float(h);
}

__device__ __forceinline__ void g2lds16(const void* g, void* l) {
  __builtin_amdgcn_global_load_lds(
      (const __attribute__((address_space(1))) unsigned int*)g,
      (__attribute__((address_space(3))) unsigned int*)l, 16, 0, 0);
}

// ---------------- workspace map (byte offsets) ----------------------------
#define WX1    0u           // fp32 x1 (2048*768)
#define WX2    6291456u     // fp32 x2
#define WQKV   12582912u    // u16 qkv_b [2080][2304]; later q2b[2048][768]+kv2b[154][1536]
#define WBB1   22167552u    // u16 comb_b / attn_b / tbuf_b
#define WG     47333376u    // u16 g_b [2048][3072]
#define WS1    59916288u    // u16 hh / x2b [2048][768]
#define WTEXT  63062016u    // u16 text_b [154][768]
#define WATT2  63298560u    // u16 attn2b [2048][768]
#define WWQKV  66444288u    // u16 wqkv_t [2304][768]
#define WWO    69983232u    // u16 wo_t   [768][768]
#define WW1    71162880u    // u16 w1_t   [6144][768]
#define WW2    80600064u    // u16 w2_t   [768][3072]
#define WCAWQ  85318656u    // u16 cawq_t [768][768]
#define WCAKV  86498304u    // u16 cakv_t [1536][768]
#define WCAWO  88857600u    // u16 cawo_t [768][768]
#define WVT1   90037248u    // u16 Vt self  [2][12][64][1088]  (3,342,336 B)
#define WVT2   93379584u    // u16 Vt cross [2][12][64][128]   (393,216 B)
// end: 93,772,800 B (< 94.6 MB proven available in R0)

// ---------------- block reduction (256 threads = 4 waves) -----------------
__device__ __forceinline__ float block_sum(float v, float* sh) {
#pragma unroll
  for (int o = 32; o > 0; o >>= 1) v += __shfl_down(v, o);
  int lane = threadIdx.x & 63, w = threadIdx.x >> 6;
  if (lane == 0) sh[w] = v;
  __syncthreads();
  float r = sh[0] + sh[1] + sh[2] + sh[3];
  __syncthreads();
  return r;
}

// ---------------- weight cast + transpose: fp32 [K][N] -> bf16 [N][K] -----
__global__ __launch_bounds__(256)
void wtrans_kernel(const float* __restrict__ in, ushort_t* __restrict__ out,
                   int K, int N) {
  __shared__ float tile[64][65];
  int k0 = blockIdx.y * 64, n0 = blockIdx.x * 64;
  int t = threadIdx.x;
#pragma unroll
  for (int p = 0; p < 16; ++p) {
    int idx = t + p * 256;
    int r = idx >> 6, c = idx & 63;
    tile[r][c] = in[(size_t)(k0 + r) * N + n0 + c];
  }
  __syncthreads();
#pragma unroll
  for (int p = 0; p < 16; ++p) {
    int idx = t + p * 256;
    int r = idx >> 6, c = idx & 63;
    out[(size_t)(n0 + r) * K + k0 + c] = f2b(tile[c][r]);
  }
}

// ---------------- LN(x) and LN(face) -> comb (bf16) -----------------------
__global__ __launch_bounds__(256)
void ln_concat_kernel(const float* __restrict__ x, const float* __restrict__ enc,
                      const float* __restrict__ g, const float* __restrict__ b,
                      ushort_t* __restrict__ comb) {
  __shared__ float sh[4];
  int r = blockIdx.x;
  int bb = r / NC_DIM, i = r % NC_DIM;
  const float* src = (i < N_DIM)
      ? (x   + ((size_t)bb * N_DIM + i) * C_DIM)
      : (enc + ((size_t)bb * L_DIM + TEXT_LEN + (i - N_DIM)) * C_DIM);
  float v[3];
#pragma unroll
  for (int j = 0; j < 3; ++j) v[j] = src[threadIdx.x + j * 256];
  float mean = block_sum(v[0] + v[1] + v[2], sh) * (1.f / C_DIM);
  float sq = 0.f;
#pragma unroll
  for (int j = 0; j < 3; ++j) { float d = v[j] - mean; sq += d * d; }
  float rstd = rsqrtf(block_sum(sq, sh) * (1.f / C_DIM) + 1e-5f);
  ushort_t* dst = comb + (size_t)r * C_DIM;
#pragma unroll
  for (int j = 0; j < 3; ++j) {
    int c = threadIdx.x + j * 256;
    dst[c] = f2b((v[j] - mean) * rstd * g[c] + b[c]);
  }
}

// ---------------- double layernorm: fp32 in -> bf16 out -------------------
__global__ __launch_bounds__(256)
void ln_double_kernel(const float* __restrict__ src,
                      const float* __restrict__ g1, const float* __restrict__ b1,
                      const float* __restrict__ g2, const float* __restrict__ b2,
                      ushort_t* __restrict__ out) {
  __shared__ float sh[4];
  const float* s = src + (size_t)blockIdx.x * C_DIM;
  float v[3];
#pragma unroll
  for (int j = 0; j < 3; ++j) v[j] = s[threadIdx.x + j * 256];
  float mean = block_sum(v[0] + v[1] + v[2], sh) * (1.f / C_DIM);
  float sq = 0.f;
#pragma unroll
  for (int j = 0; j < 3; ++j) { float d = v[j] - mean; sq += d * d; }
  float rstd = rsqrtf(block_sum(sq, sh) * (1.f / C_DIM) + 1e-5f);
  float y[3];
#pragma unroll
  for (int j = 0; j < 3; ++j) {
    int c = threadIdx.x + j * 256;
    y[j] = (v[j] - mean) * rstd * g1[c] + b1[c];
  }
  float mean2 = block_sum(y[0] + y[1] + y[2], sh) * (1.f / C_DIM);
  sq = 0.f;
#pragma unroll
  for (int j = 0; j < 3; ++j) { float d = y[j] - mean2; sq += d * d; }
  float rstd2 = rsqrtf(block_sum(sq, sh) * (1.f / C_DIM) + 1e-5f);
  ushort_t* dst = out + (size_t)blockIdx.x * C_DIM;
#pragma unroll
  for (int j = 0; j < 3; ++j) {
    int c = threadIdx.x + j * 256;
    dst[c] = f2b((y[j] - mean2) * rstd2 * g2[c] + b2[c]);
  }
}

// ---------------- bf16 MFMA GEMM (m97 structure) ---------------------------
__global__ __launch_bounds__(256)
void gemm_bf16(const ushort_t* __restrict__ A, const ushort_t* __restrict__ Bt,
               float* __restrict__ Out, ushort_t* __restrict__ Ob,
               int M, int N, int K,
               const float* __restrict__ bias, const float* __restrict__ res,
               const float* __restrict__ alphaPtr) {
  __shared__ ushort_t sA[128 * 32];
  __shared__ ushort_t sB[128 * 32];
  int t = threadIdx.x;
  int w = t >> 6, ln = t & 63;
  int m0 = blockIdx.y * 128, n0 = blockIdx.x * 128;
  int wm = (w >> 1) * 64, wn = (w & 1) * 64;
  int lr = ln & 15;
  int lq = ln >> 4;
  int seg_r = ln >> 2;
  int seg_c = (ln & 3) * 8;

  f32x4 acc[4][4];
#pragma unroll
  for (int mi = 0; mi < 4; ++mi)
#pragma unroll
    for (int ni = 0; ni < 4; ++ni) acc[mi][ni] = (f32x4){0.f, 0.f, 0.f, 0.f};

  for (int k0 = 0; k0 < K; k0 += 32) {
#pragma unroll
    for (int l = 0; l < 2; ++l) {
      int s = w * 2 + l;
      int arow = m0 + s * 16 + seg_r;
      arow = arow < M ? arow : M - 1;
      g2lds16(A + (size_t)arow * K + k0 + seg_c, sA + s * 512);
      int nrow = n0 + s * 16 + seg_r;
      g2lds16(Bt + (size_t)nrow * K + k0 + seg_c, sB + s * 512);
    }
    __syncthreads();
    bf16x8 af[4], bf[4];
#pragma unroll
    for (int mi = 0; mi < 4; ++mi)
      af[mi] = *(const bf16x8*)&sA[(wm + mi * 16 + lr) * 32 + lq * 8];
#pragma unroll
    for (int ni = 0; ni < 4; ++ni)
      bf[ni] = *(const bf16x8*)&sB[(wn + ni * 16 + lr) * 32 + lq * 8];
#pragma unroll
    for (int mi = 0; mi < 4; ++mi)
#pragma unroll
      for (int ni = 0; ni < 4; ++ni)
        acc[mi][ni] = __builtin_amdgcn_mfma_f32_16x16x32_bf16(
            af[mi], bf[ni], acc[mi][ni], 0, 0, 0);
    __syncthreads();
  }

  float f = alphaPtr ? tanhf(alphaPtr[0]) : 1.0f;
#pragma unroll
  for (int mi = 0; mi < 4; ++mi) {
#pragma unroll
    for (int ni = 0; ni < 4; ++ni) {
      int col = n0 + wn + ni * 16 + lr;
      float bv = bias ? bias[col] : 0.f;
#pragma unroll
      for (int r = 0; r < 4; ++r) {
        int row = m0 + wm + mi * 16 + lq * 4 + r;
        if (row < M) {
          float val = acc[mi][ni][r] + bv;
          if (res) val = res[(size_t)row * N + col] + f * val;
          if (Out) Out[(size_t)row * N + col] = val;
          if (Ob)  Ob[(size_t)row * N + col] = f2b(val);
        }
      }
    }
  }
}

// ---------------- V transpose: strided bf16 [key][64] -> Vt [dv][Nkp] -----
// One block per (64-key tile, h, b). Zero-fills keys >= Nk (required: PV
// multiplies pad-V by P=0; poison NaN would propagate through MFMA).
__global__ __launch_bounds__(256)
void vtrans_kernel(const ushort_t* __restrict__ V, ushort_t* __restrict__ Vt,
                   int rows_per_b, int stride, int Nk, int Nkp) {
  __shared__ ushort_t tile[64][68];
  int k0 = blockIdx.x * 64;
  int h = blockIdx.y, b = blockIdx.z;
  int t = threadIdx.x;
#pragma unroll
  for (int p = 0; p < 4; ++p) {
    int r = p * 16 + (t >> 4), c = (t & 15) * 4;
    int key = k0 + r;
    ushort4 u = make_ushort4(0, 0, 0, 0);
    if (key < Nk)
      u = *(const ushort4*)&V[((size_t)(b * rows_per_b + key)) * stride + h * 64 + c];
    *(ushort4*)&tile[r][c] = u;
  }
  __syncthreads();
  size_t base = ((size_t)(b * 12 + h)) * 64 * Nkp;
#pragma unroll
  for (int p = 0; p < 4; ++p) {
    int dv = p * 16 + (t >> 4), kc = (t & 15) * 4;
    ushort4 u;
    u.x = tile[kc + 0][dv]; u.y = tile[kc + 1][dv];
    u.z = tile[kc + 2][dv]; u.w = tile[kc + 3][dv];
    *(ushort4*)&Vt[base + (size_t)dv * Nkp + k0 + kc] = u;
  }
}

// ---------------- MFMA flash attention ------------------------------------
// Block = (64-q tile, h, b); 4 waves; wave w owns q rows [q0+w*16, +16).
// Per 64-key tile: S = Q K^T (8 MFMA), online softmax (shfl over 16-lane
// quad groups), P -> per-wave LDS (bf16, A-layout rows), O += P V (8 MFMA).
// Q/K strided bf16; Vt pre-transposed [b][h][dv][Nkp]; O bf16 [B*1024][768].
__global__ __launch_bounds__(256)
void attn_mfma(const ushort_t* __restrict__ Q, const ushort_t* __restrict__ K,
               const ushort_t* __restrict__ Vt, ushort_t* __restrict__ O,
               int q_rows_per_b, int kv_rows_per_b, int Nk, int Nkp,
               int qstride, int kstride) {
  __shared__ ushort_t sQ[2 * 64 * 32];   // [kstep d][q][32]
  __shared__ ushort_t sK[2 * 64 * 32];   // [kstep d][key][32]
  __shared__ ushort_t sV[2 * 64 * 32];   // [keystep][dv][32 keys]
  __shared__ ushort_t sP[4][2 * 16 * 32];// per-wave [keystep][q16][32]
  const float scale = 0.125f;            // 64^-0.5
  int t = threadIdx.x;
  int w = t >> 6, ln = t & 63;
  int col = ln & 15, quad = ln >> 4;
  int b = blockIdx.z, h = blockIdx.y, q0 = blockIdx.x * 64;

  // ---- stage Q once: [kstep][row=w*16+(ln>>2)][chunk=(ln&3)*8] ----
#pragma unroll
  for (int s = 0; s < 2; ++s) {
    int r = q0 + w * 16 + (ln >> 2);
    const ushort_t* gp = Q + (size_t)(b * q_rows_per_b + r) * qstride
                       + h * 64 + s * 32 + (ln & 3) * 8;
    g2lds16(gp, (char*)sQ + s * 4096 + w * 1024);
  }
  __syncthreads();
  bf16x8 qa[2];
#pragma unroll
  for (int s = 0; s < 2; ++s)
    qa[s] = *(const bf16x8*)&sQ[s * 2048 + (w * 16 + col) * 32 + quad * 8];

  f32x4 oacc[4];
#pragma unroll
  for (int i = 0; i < 4; ++i) oacc[i] = (f32x4){0.f, 0.f, 0.f, 0.f};
  float m_i[4], l_i[4];
#pragma unroll
  for (int r = 0; r < 4; ++r) { m_i[r] = -1e30f; l_i[r] = 0.f; }

  ushort_t* sPw = sP[w];
  size_t vt_base = ((size_t)(b * 12 + h)) * 64 * Nkp;
  int ntiles = Nkp >> 6;

  for (int kt = 0; kt < ntiles; ++kt) {
    __syncthreads();   // prior tile's frag reads done before restaging
    // ---- stage K tile (rows may run past Nk: garbage, masked below) ----
#pragma unroll
    for (int s = 0; s < 2; ++s) {
      int key = kt * 64 + w * 16 + (ln >> 2);
      const ushort_t* gp = K + (size_t)(b * kv_rows_per_b + key) * kstride
                         + h * 64 + s * 32 + (ln & 3) * 8;
      g2lds16(gp, (char*)sK + s * 4096 + w * 1024);
    }
    // ---- stage Vt tile: [keystep][dv=w*16+(ln>>2)][(ln&3)*8 keys] ----
#pragma unroll
    for (int s = 0; s < 2; ++s) {
      int dv = w * 16 + (ln >> 2);
      const ushort_t* gp = Vt + vt_base + (size_t)dv * Nkp
                         + kt * 64 + s * 32 + (ln & 3) * 8;
      g2lds16(gp, (char*)sV + s * 4096 + w * 1024);
    }
    __syncthreads();

    // ---- S = Q K^T : cs[nblk][r] = S[q=quad*4+r][key=nblk*16+col] ----
    f32x4 cs[4];
#pragma unroll
    for (int nblk = 0; nblk < 4; ++nblk) {
      cs[nblk] = (f32x4){0.f, 0.f, 0.f, 0.f};
#pragma unroll
      for (int s = 0; s < 2; ++s) {
        bf16x8 kb = *(const bf16x8*)&sK[s * 2048 + (nblk * 16 + col) * 32 + quad * 8];
        cs[nblk] = __builtin_amdgcn_mfma_f32_16x16x32_bf16(qa[s], kb, cs[nblk], 0, 0, 0);
      }
    }
    // ---- scale + mask (select, not arithmetic: kills garbage/NaN) ----
#pragma unroll
    for (int nblk = 0; nblk < 4; ++nblk) {
      bool valid = (kt * 64 + nblk * 16 + col) < Nk;
#pragma unroll
      for (int r = 0; r < 4; ++r)
        cs[nblk][r] = valid ? cs[nblk][r] * scale : -1e30f;
    }
    // ---- online softmax per q row r (16-lane quad group) ----
#pragma unroll
    for (int r = 0; r < 4; ++r) {
      float rm = fmaxf(fmaxf(cs[0][r], cs[1][r]), fmaxf(cs[2][r], cs[3][r]));
#pragma unroll
      for (int o = 1; o < 16; o <<= 1) rm = fmaxf(rm, __shfl_xor(rm, o));
      float mnew = fmaxf(m_i[r], rm);
      float alpha = __expf(m_i[r] - mnew);
      float ps = 0.f;
#pragma unroll
      for (int nblk = 0; nblk < 4; ++nblk) {
        float p = __expf(cs[nblk][r] - mnew);
        cs[nblk][r] = p; ps += p;
      }
#pragma unroll
      for (int o = 1; o < 16; o <<= 1) ps += __shfl_xor(ps, o);
      l_i[r] = l_i[r] * alpha + ps;
      m_i[r] = mnew;
#pragma unroll
      for (int nblk = 0; nblk < 4; ++nblk) oacc[nblk][r] *= alpha;
    }
    // ---- P (bf16) -> per-wave LDS in A-layout rows ----
#pragma unroll
    for (int nblk = 0; nblk < 4; ++nblk) {
      int s = nblk >> 1, kin = (nblk & 1) * 16 + col;
#pragma unroll
      for (int r = 0; r < 4; ++r)
        sPw[s * 512 + (quad * 4 + r) * 32 + kin] = f2b(cs[nblk][r]);
    }
    // ---- O += P V ----
#pragma unroll
    for (int s = 0; s < 2; ++s) {
      bf16x8 pa = *(const bf16x8*)&sPw[s * 512 + col * 32 + quad * 8];
#pragma unroll
      for (int nblk = 0; nblk < 4; ++nblk) {
        bf16x8 vb = *(const bf16x8*)&sV[s * 2048 + (nblk * 16 + col) * 32 + quad * 8];
        oacc[nblk] = __builtin_amdgcn_mfma_f32_16x16x32_bf16(pa, vb, oacc[nblk], 0, 0, 0);
      }
    }
  }

  // ---- epilogue: O[q][dv] = oacc / l ----
#pragma unroll
  for (int r = 0; r < 4; ++r) {
    float inv = 1.f / l_i[r];
    int row = b * N_DIM + q0 + w * 16 + quad * 4 + r;
#pragma unroll
    for (int nblk = 0; nblk < 4; ++nblk)
      O[(size_t)row * C_DIM + h * 64 + nblk * 16 + col] = f2b(oacc[nblk][r] * inv);
  }
}

// ---------------- GEGLU: bf16 in [2048][6144] -> bf16 out [2048][3072] ----
__global__ __launch_bounds__(256)
void geglu_kernel(const ushort_t* __restrict__ tbuf, ushort_t* __restrict__ g) {
  int idx = blockIdx.x * 256 + threadIdx.x;
  int r = idx / INNER, c = idx % INNER;
  float a = b2f(tbuf[(size_t)r * (2 * INNER) + c]);
  float x = b2f(tbuf[(size_t)r * (2 * INNER) + INNER + c]);
  float ge = 0.5f * x * (1.f + erff(x * 0.70710678118654752f));
  g[idx] = f2b(a * ge);
}

// ---------------- text gather: fp32 -> bf16 compact (154,768) -------------
__global__ __launch_bounds__(256)
void gather_text_kernel(const float* __restrict__ enc, ushort_t* __restrict__ out) {
  int r = blockIdx.x;
  int bb = r / TEXT_LEN, j = r % TEXT_LEN;
  const float* src = enc + ((size_t)bb * L_DIM + j) * C_DIM;
  ushort_t* dst = out + (size_t)r * C_DIM;
#pragma unroll
  for (int l = 0; l < 3; ++l) {
    int c = threadIdx.x + l * 256;
    dst[c] = f2b(src[c]);
  }
}

// ---------------------------------------------------------------------------
extern "C" void kernel_launch(void* const* d_in, const int* in_sizes, int n_in,
                              void* d_out, int out_size, void* d_ws, size_t ws_size,
                              hipStream_t stream) {
  const float* x        = (const float*)d_in[0];
  const float* enc      = (const float*)d_in[1];
  const float* ln1_g    = (const float*)d_in[2];
  const float* ln1_b    = (const float*)d_in[3];
  const float* ln2_g    = (const float*)d_in[4];
  const float* ln2_b    = (const float*)d_in[5];
  const float* sa_wq    = (const float*)d_in[6];
  const float* sa_wk    = (const float*)d_in[7];
  const float* sa_wv    = (const float*)d_in[8];
  const float* sa_wo    = (const float*)d_in[9];
  const float* sa_wo_b  = (const float*)d_in[10];
  const float* ff_ln_g  = (const float*)d_in[11];
  const float* ff_ln_b  = (const float*)d_in[12];
  const float* ff_w1    = (const float*)d_in[13];
  const float* ff_w2    = (const float*)d_in[14];
  const float* a_attn   = (const float*)d_in[15];
  const float* a_dense  = (const float*)d_in[16];
  const float* ca_wq    = (const float*)d_in[17];
  const float* ca_wk    = (const float*)d_in[18];
  const float* ca_wv    = (const float*)d_in[19];
  const float* ca_wo    = (const float*)d_in[20];
  const float* ca_wo_b  = (const float*)d_in[21];

  char* ws = (char*)d_ws;
  float*    x1     = (float*)(ws + WX1);
  float*    x2     = (float*)(ws + WX2);
  ushort_t* qkv_b  = (ushort_t*)(ws + WQKV);
  ushort_t* q2b    = (ushort_t*)(ws + WQKV);
  ushort_t* kv2b   = (ushort_t*)(ws + WQKV + 3145728u);
  ushort_t* comb_b = (ushort_t*)(ws + WBB1);
  ushort_t* attn_b = (ushort_t*)(ws + WBB1);
  ushort_t* tbuf_b = (ushort_t*)(ws + WBB1);
  ushort_t* g_b    = (ushort_t*)(ws + WG);
  ushort_t* hh     = (ushort_t*)(ws + WS1);
  ushort_t* x2b    = (ushort_t*)(ws + WS1);
  ushort_t* text_b = (ushort_t*)(ws + WTEXT);
  ushort_t* attn2b = (ushort_t*)(ws + WATT2);
  ushort_t* wqkv_t = (ushort_t*)(ws + WWQKV);
  ushort_t* wo_t   = (ushort_t*)(ws + WWO);
  ushort_t* w1_t   = (ushort_t*)(ws + WW1);
  ushort_t* w2_t   = (ushort_t*)(ws + WW2);
  ushort_t* cawq_t = (ushort_t*)(ws + WCAWQ);
  ushort_t* cakv_t = (ushort_t*)(ws + WCAKV);
  ushort_t* cawo_t = (ushort_t*)(ws + WCAWO);
  ushort_t* vt1    = (ushort_t*)(ws + WVT1);
  ushort_t* vt2    = (ushort_t*)(ws + WVT2);
  float* out = (float*)d_out;

  const int Mc = B_DIM * NC_DIM;   // 2080
  const int Mx = B_DIM * N_DIM;    // 2048
  const int Mt = B_DIM * TEXT_LEN; // 154

  // ---- weight casts + transposes (fp32 [K][N] -> bf16 [N][K]) ----
  dim3 tg(12, 12);
  wtrans_kernel<<<tg, 256, 0, stream>>>(sa_wq, wqkv_t + 0 * 589824, C_DIM, C_DIM);
  wtrans_kernel<<<tg, 256, 0, stream>>>(sa_wk, wqkv_t + 1 * 589824, C_DIM, C_DIM);
  wtrans_kernel<<<tg, 256, 0, stream>>>(sa_wv, wqkv_t + 2 * 589824, C_DIM, C_DIM);
  wtrans_kernel<<<tg, 256, 0, stream>>>(sa_wo, wo_t, C_DIM, C_DIM);
  wtrans_kernel<<<dim3(96, 12), 256, 0, stream>>>(ff_w1, w1_t, C_DIM, 2 * INNER);
  wtrans_kernel<<<dim3(12, 48), 256, 0, stream>>>(ff_w2, w2_t, INNER, C_DIM);
  wtrans_kernel<<<tg, 256, 0, stream>>>(ca_wq, cawq_t, C_DIM, C_DIM);
  wtrans_kernel<<<tg, 256, 0, stream>>>(ca_wk, cakv_t + 0 * 589824, C_DIM, C_DIM);
  wtrans_kernel<<<tg, 256, 0, stream>>>(ca_wv, cakv_t + 1 * 589824, C_DIM, C_DIM);
  wtrans_kernel<<<tg, 256, 0, stream>>>(ca_wo, cawo_t, C_DIM, C_DIM);

  // ---- pipeline ----
  ln_concat_kernel<<<Mc, 256, 0, stream>>>(x, enc, ln1_g, ln1_b, comb_b);
  gemm_bf16<<<dim3(2304 / 128, (Mc + 127) / 128), 256, 0, stream>>>(
      comb_b, wqkv_t, nullptr, qkv_b, Mc, 2304, C_DIM, nullptr, nullptr, nullptr);
  // self-attn: V transpose then MFMA flash (Nk=1040, Nkp=1088)
  vtrans_kernel<<<dim3(17, 12, B_DIM), 256, 0, stream>>>(
      qkv_b + 1536, vt1, NC_DIM, 2304, NC_DIM, 1088);
  attn_mfma<<<dim3(N_DIM / 64, 12, B_DIM), 256, 0, stream>>>(
      qkv_b + 0, qkv_b + 768, vt1, attn_b, NC_DIM, NC_DIM, NC_DIM, 1088, 2304, 2304);
  gemm_bf16<<<dim3(768 / 128, Mx / 128), 256, 0, stream>>>(
      attn_b, wo_t, x1, nullptr, Mx, C_DIM, C_DIM, sa_wo_b, x, a_attn);
  ln_double_kernel<<<Mx, 256, 0, stream>>>(x1, ln2_g, ln2_b, ff_ln_g, ff_ln_b, hh);
  gemm_bf16<<<dim3(6144 / 128, Mx / 128), 256, 0, stream>>>(
      hh, w1_t, nullptr, tbuf_b, Mx, 2 * INNER, C_DIM, nullptr, nullptr, nullptr);
  geglu_kernel<<<(Mx * INNER) / 256, 256, 0, stream>>>(tbuf_b, g_b);
  gemm_bf16<<<dim3(768 / 128, Mx / 128), 256, 0, stream>>>(
      g_b, w2_t, x2, x2b, Mx, C_DIM, INNER, nullptr, x1, a_dense);
  gather_text_kernel<<<Mt, 256, 0, stream>>>(enc, text_b);
  gemm_bf16<<<dim3(768 / 128, Mx / 128), 256, 0, stream>>>(
      x2b, cawq_t, nullptr, q2b, Mx, C_DIM, C_DIM, nullptr, nullptr, nullptr);
  gemm_bf16<<<dim3(1536 / 128, (Mt + 127) / 128), 256, 0, stream>>>(
      text_b, cakv_t, nullptr, kv2b, Mt, 1536, C_DIM, nullptr, nullptr, nullptr);
  // cross-attn: Nk=77, Nkp=128
  vtrans_kernel<<<dim3(2, 12, B_DIM), 256, 0, stream>>>(
      kv2b + 768, vt2, TEXT_LEN, 1536, TEXT_LEN, 128);
  attn_mfma<<<dim3(N_DIM / 64, 12, B_DIM), 256, 0, stream>>>(
      q2b, kv2b + 0, vt2, attn2b, N_DIM, TEXT_LEN, TEXT_LEN, 128, 768, 1536);
  gemm_bf16<<<dim3(768 / 128, Mx / 128), 256, 0, stream>>>(
      attn2b, cawo_t, out, nullptr, Mx, C_DIM, C_DIM, ca_wo_b, x2, nullptr);
}

// Round 5
// 451.994 us; speedup vs baseline: 5.6761x; 1.1791x over previous
//
#include <hip/hip_runtime.h>
#include <hip/hip_bf16.h>
#include <math.h>

// ---------------------------------------------------------------------------
// FaceAttnProcessor forward. R4: split-K (fp32 atomic) for grid-starved
// N=768 GEMMs + double-buffered LDS K-loop + batched weight transpose.
// Attention = R3 MFMA flash. B=2, N=1024, C=768, H=12, d=64, INNER=3072.
// ---------------------------------------------------------------------------

#define C_DIM 768
#define B_DIM 2
#define N_DIM 1024
#define NC_DIM 1040
#define L_DIM 93
#define TEXT_LEN 77
#define INNER 3072

typedef unsigned short ushort_t;
typedef __bf16 bf16x8 __attribute__((ext_vector_type(8)));
typedef float f32x4 __attribute__((ext_vector_type(4)));

__device__ __forceinline__ ushort_t f2b(float f) {
  __hip_bfloat16 h = __float2bfloat16(f);
  return *(ushort_t*)&h;
}
__device__ __forceinline__ float b2f(ushort_t u) {
  __hip_bfloat16 h = *(__hip_bfloat16*)&u;
  return __bfloat162float(h);
}

__device__ __forceinline__ void g2lds16(const void* g, void* l) {
  __builtin_amdgcn_global_load_lds(
      (const __attribute__((address_space(1))) unsigned int*)g,
      (__attribute__((address_space(3))) unsigned int*)l, 16, 0, 0);
}

// ---------------- workspace map (byte offsets) ----------------------------
#define WX1    0u           // fp32 x1 (2048*768)
#define WX2    6291456u     // fp32 x2
#define WQKV   12582912u    // u16 qkv_b [2080][2304]; later q2b/kv2b; ff2-acc overlay
#define WBB1   22167552u    // u16 comb_b / attn_b / tbuf_b; later q2-acc/fin-acc
#define WG     47333376u    // u16 g_b [2048][3072]; earlier wo-acc overlay
#define WS1    59916288u    // u16 hh / x2b [2048][768]
#define WTEXT  63062016u    // u16 text_b [154][768]
#define WATT2  63298560u    // u16 attn2b [2048][768]
#define WWQKV  66444288u    // u16 wqkv_t [2304][768]
#define WWO    69983232u    // u16 wo_t   [768][768]
#define WW1    71162880u    // u16 w1_t   [6144][768]
#define WW2    80600064u    // u16 w2_t   [768][3072]
#define WCAWQ  85318656u    // u16 cawq_t [768][768]
#define WCAKV  86498304u    // u16 cakv_t [1536][768]
#define WCAWO  88857600u    // u16 cawo_t [768][768]
#define WVT1   90037248u    // u16 Vt self  [2][12][64][1088]
#define WVT2   93379584u    // u16 Vt cross [2][12][64][128]
// accumulator overlays (6.29 MB each, fp32 2048x768):
#define WACC_WO   WG                    // live: wo gemm -> wo epi (g_b not yet written)
#define WACC_FF2  WQKV                  // live: ff2 gemm -> ff2 epi (qkv_b dead)
#define WACC_Q2   WBB1                  // live: q2 gemm -> q2 epi (attn_b/tbuf_b dead)
#define WACC_FIN  (WBB1 + 6291456u)     // live: final gemm -> final epi
// end: 93,772,800 B

// ---------------- block reduction (256 threads = 4 waves) -----------------
__device__ __forceinline__ float block_sum(float v, float* sh) {
#pragma unroll
  for (int o = 32; o > 0; o >>= 1) v += __shfl_down(v, o);
  int lane = threadIdx.x & 63, w = threadIdx.x >> 6;
  if (lane == 0) sh[w] = v;
  __syncthreads();
  float r = sh[0] + sh[1] + sh[2] + sh[3];
  __syncthreads();
  return r;
}

// ---------------- batched weight cast+transpose ---------------------------
// 10 jobs, each fp32 [K][N] -> bf16 [N][K], 64x64 tiles, one flat grid.
struct WtDesc {
  const float* src[10];
  ushort_t*    dst[10];
  int K[10];
  int N[10];
  int tilesX[10];
  int start[11];
};

__global__ __launch_bounds__(256)
void wtrans_batched(WtDesc d) {
  __shared__ float tile[64][65];
  int bid = blockIdx.x;
  int j = 0;
  while (j < 9 && bid >= d.start[j + 1]) ++j;
  int ti = bid - d.start[j];
  int K = d.K[j], N = d.N[j];
  int n0 = (ti % d.tilesX[j]) * 64, k0 = (ti / d.tilesX[j]) * 64;
  const float* in = d.src[j];
  ushort_t* out = d.dst[j];
  int t = threadIdx.x;
#pragma unroll
  for (int p = 0; p < 16; ++p) {
    int idx = t + p * 256;
    int r = idx >> 6, c = idx & 63;
    tile[r][c] = in[(size_t)(k0 + r) * N + n0 + c];
  }
  __syncthreads();
#pragma unroll
  for (int p = 0; p < 16; ++p) {
    int idx = t + p * 256;
    int r = idx >> 6, c = idx & 63;
    out[(size_t)(n0 + r) * K + k0 + c] = f2b(tile[c][r]);
  }
}

// ---------------- LN(x) and LN(face) -> comb (bf16) -----------------------
__global__ __launch_bounds__(256)
void ln_concat_kernel(const float* __restrict__ x, const float* __restrict__ enc,
                      const float* __restrict__ g, const float* __restrict__ b,
                      ushort_t* __restrict__ comb) {
  __shared__ float sh[4];
  int r = blockIdx.x;
  int bb = r / NC_DIM, i = r % NC_DIM;
  const float* src = (i < N_DIM)
      ? (x   + ((size_t)bb * N_DIM + i) * C_DIM)
      : (enc + ((size_t)bb * L_DIM + TEXT_LEN + (i - N_DIM)) * C_DIM);
  float v[3];
#pragma unroll
  for (int j = 0; j < 3; ++j) v[j] = src[threadIdx.x + j * 256];
  float mean = block_sum(v[0] + v[1] + v[2], sh) * (1.f / C_DIM);
  float sq = 0.f;
#pragma unroll
  for (int j = 0; j < 3; ++j) { float d = v[j] - mean; sq += d * d; }
  float rstd = rsqrtf(block_sum(sq, sh) * (1.f / C_DIM) + 1e-5f);
  ushort_t* dst = comb + (size_t)r * C_DIM;
#pragma unroll
  for (int j = 0; j < 3; ++j) {
    int c = threadIdx.x + j * 256;
    dst[c] = f2b((v[j] - mean) * rstd * g[c] + b[c]);
  }
}

// ---------------- double layernorm: fp32 in -> bf16 out -------------------
__global__ __launch_bounds__(256)
void ln_double_kernel(const float* __restrict__ src,
                      const float* __restrict__ g1, const float* __restrict__ b1,
                      const float* __restrict__ g2, const float* __restrict__ b2,
                      ushort_t* __restrict__ out) {
  __shared__ float sh[4];
  const float* s = src + (size_t)blockIdx.x * C_DIM;
  float v[3];
#pragma unroll
  for (int j = 0; j < 3; ++j) v[j] = s[threadIdx.x + j * 256];
  float mean = block_sum(v[0] + v[1] + v[2], sh) * (1.f / C_DIM);
  float sq = 0.f;
#pragma unroll
  for (int j = 0; j < 3; ++j) { float d = v[j] - mean; sq += d * d; }
  float rstd = rsqrtf(block_sum(sq, sh) * (1.f / C_DIM) + 1e-5f);
  float y[3];
#pragma unroll
  for (int j = 0; j < 3; ++j) {
    int c = threadIdx.x + j * 256;
    y[j] = (v[j] - mean) * rstd * g1[c] + b1[c];
  }
  float mean2 = block_sum(y[0] + y[1] + y[2], sh) * (1.f / C_DIM);
  sq = 0.f;
#pragma unroll
  for (int j = 0; j < 3; ++j) { float d = y[j] - mean2; sq += d * d; }
  float rstd2 = rsqrtf(block_sum(sq, sh) * (1.f / C_DIM) + 1e-5f);
  ushort_t* dst = out + (size_t)blockIdx.x * C_DIM;
#pragma unroll
  for (int j = 0; j < 3; ++j) {
    int c = threadIdx.x + j * 256;
    dst[c] = f2b((y[j] - mean2) * rstd2 * g2[c] + b2[c]);
  }
}

// ---------------- bf16 MFMA GEMM, double-buffered, optional split-K --------
// grid.z = nsplit; each block covers K range [z*Ksplit, min(K,(z+1)*Ksplit)).
// Acc != null: partials via fp32 atomicAdd (bias/res applied in splitk_epi).
// Acc == null: fused epilogue as before.
__global__ __launch_bounds__(256)
void gemm_bf16(const ushort_t* __restrict__ A, const ushort_t* __restrict__ Bt,
               float* __restrict__ Out, ushort_t* __restrict__ Ob,
               float* __restrict__ Acc,
               int M, int N, int K, int Ksplit,
               const float* __restrict__ bias, const float* __restrict__ res,
               const float* __restrict__ alphaPtr) {
  __shared__ ushort_t sA[2][128 * 32];
  __shared__ ushort_t sB[2][128 * 32];
  int t = threadIdx.x;
  int w = t >> 6, ln = t & 63;
  int m0 = blockIdx.y * 128, n0 = blockIdx.x * 128;
  int wm = (w >> 1) * 64, wn = (w & 1) * 64;
  int lr = ln & 15, lq = ln >> 4;
  int seg_r = ln >> 2, seg_c = (ln & 3) * 8;
  int kbeg = blockIdx.z * Ksplit;
  int kend = kbeg + Ksplit; if (kend > K) kend = K;

  f32x4 acc[4][4];
#pragma unroll
  for (int mi = 0; mi < 4; ++mi)
#pragma unroll
    for (int ni = 0; ni < 4; ++ni) acc[mi][ni] = (f32x4){0.f, 0.f, 0.f, 0.f};

#define STAGE(k0_, buf_)                                                     \
  do {                                                                       \
    _Pragma("unroll") for (int l = 0; l < 2; ++l) {                          \
      int s = w * 2 + l;                                                     \
      int arow = m0 + s * 16 + seg_r;                                        \
      arow = arow < M ? arow : M - 1;                                        \
      g2lds16(A + (size_t)arow * K + (k0_) + seg_c, &sA[buf_][s * 512]);     \
      int nrow = n0 + s * 16 + seg_r;                                        \
      g2lds16(Bt + (size_t)nrow * K + (k0_) + seg_c, &sB[buf_][s * 512]);    \
    }                                                                        \
  } while (0)

  STAGE(kbeg, 0);
  __syncthreads();
  int cur = 0;
  for (int k0 = kbeg; k0 < kend; k0 += 32) {
    if (k0 + 32 < kend) STAGE(k0 + 32, cur ^ 1);   // prefetch next tile
    bf16x8 af[4], bfr[4];
#pragma unroll
    for (int mi = 0; mi < 4; ++mi)
      af[mi] = *(const bf16x8*)&sA[cur][(wm + mi * 16 + lr) * 32 + lq * 8];
#pragma unroll
    for (int ni = 0; ni < 4; ++ni)
      bfr[ni] = *(const bf16x8*)&sB[cur][(wn + ni * 16 + lr) * 32 + lq * 8];
#pragma unroll
    for (int mi = 0; mi < 4; ++mi)
#pragma unroll
      for (int ni = 0; ni < 4; ++ni)
        acc[mi][ni] = __builtin_amdgcn_mfma_f32_16x16x32_bf16(
            af[mi], bfr[ni], acc[mi][ni], 0, 0, 0);
    __syncthreads();   // drains prefetch vmcnt + protects LDS reuse
    cur ^= 1;
  }
#undef STAGE

  if (Acc) {
#pragma unroll
    for (int mi = 0; mi < 4; ++mi)
#pragma unroll
      for (int ni = 0; ni < 4; ++ni) {
        int col = n0 + wn + ni * 16 + lr;
#pragma unroll
        for (int r = 0; r < 4; ++r) {
          int row = m0 + wm + mi * 16 + lq * 4 + r;
          if (row < M) unsafeAtomicAdd(&Acc[(size_t)row * N + col], acc[mi][ni][r]);
        }
      }
  } else {
    float f = alphaPtr ? tanhf(alphaPtr[0]) : 1.0f;
#pragma unroll
    for (int mi = 0; mi < 4; ++mi)
#pragma unroll
      for (int ni = 0; ni < 4; ++ni) {
        int col = n0 + wn + ni * 16 + lr;
        float bv = bias ? bias[col] : 0.f;
#pragma unroll
        for (int r = 0; r < 4; ++r) {
          int row = m0 + wm + mi * 16 + lq * 4 + r;
          if (row < M) {
            float val = acc[mi][ni][r] + bv;
            if (res) val = res[(size_t)row * N + col] + f * val;
            if (Out) Out[(size_t)row * N + col] = val;
            if (Ob)  Ob[(size_t)row * N + col] = f2b(val);
          }
        }
      }
  }
}

// ---------------- split-K epilogue: acc -> bias/res/alpha -> out -----------
__global__ __launch_bounds__(256)
void splitk_epi(const float* __restrict__ Acc, float* __restrict__ Out,
                ushort_t* __restrict__ Ob, int MN, int N,
                const float* __restrict__ bias, const float* __restrict__ res,
                const float* __restrict__ alphaPtr) {
  int idx = (blockIdx.x * 256 + threadIdx.x) * 4;
  if (idx >= MN) return;
  float f = alphaPtr ? tanhf(alphaPtr[0]) : 1.0f;
  float4 a = *(const float4*)&Acc[idx];
  float v[4] = {a.x, a.y, a.z, a.w};
  if (bias) {
    int col = idx % N;
    float4 bb = *(const float4*)&bias[col];
    v[0] += bb.x; v[1] += bb.y; v[2] += bb.z; v[3] += bb.w;
  }
  if (res) {
    float4 rr = *(const float4*)&res[idx];
    v[0] = rr.x + f * v[0]; v[1] = rr.y + f * v[1];
    v[2] = rr.z + f * v[2]; v[3] = rr.w + f * v[3];
  }
  if (Out) *(float4*)&Out[idx] = make_float4(v[0], v[1], v[2], v[3]);
  if (Ob) {
    ushort4 o;
    o.x = f2b(v[0]); o.y = f2b(v[1]); o.z = f2b(v[2]); o.w = f2b(v[3]);
    *(ushort4*)&Ob[idx] = o;
  }
}

// ---------------- V transpose: strided bf16 [key][64] -> Vt [dv][Nkp] -----
__global__ __launch_bounds__(256)
void vtrans_kernel(const ushort_t* __restrict__ V, ushort_t* __restrict__ Vt,
                   int rows_per_b, int stride, int Nk, int Nkp) {
  __shared__ ushort_t tile[64][68];
  int k0 = blockIdx.x * 64;
  int h = blockIdx.y, b = blockIdx.z;
  int t = threadIdx.x;
#pragma unroll
  for (int p = 0; p < 4; ++p) {
    int r = p * 16 + (t >> 4), c = (t & 15) * 4;
    int key = k0 + r;
    ushort4 u = make_ushort4(0, 0, 0, 0);
    if (key < Nk)
      u = *(const ushort4*)&V[((size_t)(b * rows_per_b + key)) * stride + h * 64 + c];
    *(ushort4*)&tile[r][c] = u;
  }
  __syncthreads();
  size_t base = ((size_t)(b * 12 + h)) * 64 * Nkp;
#pragma unroll
  for (int p = 0; p < 4; ++p) {
    int dv = p * 16 + (t >> 4), kc = (t & 15) * 4;
    ushort4 u;
    u.x = tile[kc + 0][dv]; u.y = tile[kc + 1][dv];
    u.z = tile[kc + 2][dv]; u.w = tile[kc + 3][dv];
    *(ushort4*)&Vt[base + (size_t)dv * Nkp + k0 + kc] = u;
  }
}

// ---------------- MFMA flash attention (R3, unchanged) --------------------
__global__ __launch_bounds__(256)
void attn_mfma(const ushort_t* __restrict__ Q, const ushort_t* __restrict__ K,
               const ushort_t* __restrict__ Vt, ushort_t* __restrict__ O,
               int q_rows_per_b, int kv_rows_per_b, int Nk, int Nkp,
               int qstride, int kstride) {
  __shared__ ushort_t sQ[2 * 64 * 32];
  __shared__ ushort_t sK[2 * 64 * 32];
  __shared__ ushort_t sV[2 * 64 * 32];
  __shared__ ushort_t sP[4][2 * 16 * 32];
  const float scale = 0.125f;
  int t = threadIdx.x;
  int w = t >> 6, ln = t & 63;
  int col = ln & 15, quad = ln >> 4;
  int b = blockIdx.z, h = blockIdx.y, q0 = blockIdx.x * 64;

#pragma unroll
  for (int s = 0; s < 2; ++s) {
    int r = q0 + w * 16 + (ln >> 2);
    const ushort_t* gp = Q + (size_t)(b * q_rows_per_b + r) * qstride
                       + h * 64 + s * 32 + (ln & 3) * 8;
    g2lds16(gp, (char*)sQ + s * 4096 + w * 1024);
  }
  __syncthreads();
  bf16x8 qa[2];
#pragma unroll
  for (int s = 0; s < 2; ++s)
    qa[s] = *(const bf16x8*)&sQ[s * 2048 + (w * 16 + col) * 32 + quad * 8];

  f32x4 oacc[4];
#pragma unroll
  for (int i = 0; i < 4; ++i) oacc[i] = (f32x4){0.f, 0.f, 0.f, 0.f};
  float m_i[4], l_i[4];
#pragma unroll
  for (int r = 0; r < 4; ++r) { m_i[r] = -1e30f; l_i[r] = 0.f; }

  ushort_t* sPw = sP[w];
  size_t vt_base = ((size_t)(b * 12 + h)) * 64 * Nkp;
  int ntiles = Nkp >> 6;

  for (int kt = 0; kt < ntiles; ++kt) {
    __syncthreads();
#pragma unroll
    for (int s = 0; s < 2; ++s) {
      int key = kt * 64 + w * 16 + (ln >> 2);
      const ushort_t* gp = K + (size_t)(b * kv_rows_per_b + key) * kstride
                         + h * 64 + s * 32 + (ln & 3) * 8;
      g2lds16(gp, (char*)sK + s * 4096 + w * 1024);
    }
#pragma unroll
    for (int s = 0; s < 2; ++s) {
      int dv = w * 16 + (ln >> 2);
      const ushort_t* gp = Vt + vt_base + (size_t)dv * Nkp
                         + kt * 64 + s * 32 + (ln & 3) * 8;
      g2lds16(gp, (char*)sV + s * 4096 + w * 1024);
    }
    __syncthreads();

    f32x4 cs[4];
#pragma unroll
    for (int nblk = 0; nblk < 4; ++nblk) {
      cs[nblk] = (f32x4){0.f, 0.f, 0.f, 0.f};
#pragma unroll
      for (int s = 0; s < 2; ++s) {
        bf16x8 kb = *(const bf16x8*)&sK[s * 2048 + (nblk * 16 + col) * 32 + quad * 8];
        cs[nblk] = __builtin_amdgcn_mfma_f32_16x16x32_bf16(qa[s], kb, cs[nblk], 0, 0, 0);
      }
    }
#pragma unroll
    for (int nblk = 0; nblk < 4; ++nblk) {
      bool valid = (kt * 64 + nblk * 16 + col) < Nk;
#pragma unroll
      for (int r = 0; r < 4; ++r)
        cs[nblk][r] = valid ? cs[nblk][r] * scale : -1e30f;
    }
#pragma unroll
    for (int r = 0; r < 4; ++r) {
      float rm = fmaxf(fmaxf(cs[0][r], cs[1][r]), fmaxf(cs[2][r], cs[3][r]));
#pragma unroll
      for (int o = 1; o < 16; o <<= 1) rm = fmaxf(rm, __shfl_xor(rm, o));
      float mnew = fmaxf(m_i[r], rm);
      float alpha = __expf(m_i[r] - mnew);
      float ps = 0.f;
#pragma unroll
      for (int nblk = 0; nblk < 4; ++nblk) {
        float p = __expf(cs[nblk][r] - mnew);
        cs[nblk][r] = p; ps += p;
      }
#pragma unroll
      for (int o = 1; o < 16; o <<= 1) ps += __shfl_xor(ps, o);
      l_i[r] = l_i[r] * alpha + ps;
      m_i[r] = mnew;
#pragma unroll
      for (int nblk = 0; nblk < 4; ++nblk) oacc[nblk][r] *= alpha;
    }
#pragma unroll
    for (int nblk = 0; nblk < 4; ++nblk) {
      int s = nblk >> 1, kin = (nblk & 1) * 16 + col;
#pragma unroll
      for (int r = 0; r < 4; ++r)
        sPw[s * 512 + (quad * 4 + r) * 32 + kin] = f2b(cs[nblk][r]);
    }
#pragma unroll
    for (int s = 0; s < 2; ++s) {
      bf16x8 pa = *(const bf16x8*)&sPw[s * 512 + col * 32 + quad * 8];
#pragma unroll
      for (int nblk = 0; nblk < 4; ++nblk) {
        bf16x8 vb = *(const bf16x8*)&sV[s * 2048 + (nblk * 16 + col) * 32 + quad * 8];
        oacc[nblk] = __builtin_amdgcn_mfma_f32_16x16x32_bf16(pa, vb, oacc[nblk], 0, 0, 0);
      }
    }
  }

#pragma unroll
  for (int r = 0; r < 4; ++r) {
    float inv = 1.f / l_i[r];
    int row = b * N_DIM + q0 + w * 16 + quad * 4 + r;
#pragma unroll
    for (int nblk = 0; nblk < 4; ++nblk)
      O[(size_t)row * C_DIM + h * 64 + nblk * 16 + col] = f2b(oacc[nblk][r] * inv);
  }
}

// ---------------- GEGLU ----------------------------------------------------
__global__ __launch_bounds__(256)
void geglu_kernel(const ushort_t* __restrict__ tbuf, ushort_t* __restrict__ g) {
  int idx = blockIdx.x * 256 + threadIdx.x;
  int r = idx / INNER, c = idx % INNER;
  float a = b2f(tbuf[(size_t)r * (2 * INNER) + c]);
  float x = b2f(tbuf[(size_t)r * (2 * INNER) + INNER + c]);
  float ge = 0.5f * x * (1.f + erff(x * 0.70710678118654752f));
  g[idx] = f2b(a * ge);
}

// ---------------- text gather ----------------------------------------------
__global__ __launch_bounds__(256)
void gather_text_kernel(const float* __restrict__ enc, ushort_t* __restrict__ out) {
  int r = blockIdx.x;
  int bb = r / TEXT_LEN, j = r % TEXT_LEN;
  const float* src = enc + ((size_t)bb * L_DIM + j) * C_DIM;
  ushort_t* dst = out + (size_t)r * C_DIM;
#pragma unroll
  for (int l = 0; l < 3; ++l) {
    int c = threadIdx.x + l * 256;
    dst[c] = f2b(src[c]);
  }
}

// ---------------------------------------------------------------------------
extern "C" void kernel_launch(void* const* d_in, const int* in_sizes, int n_in,
                              void* d_out, int out_size, void* d_ws, size_t ws_size,
                              hipStream_t stream) {
  const float* x        = (const float*)d_in[0];
  const float* enc      = (const float*)d_in[1];
  const float* ln1_g    = (const float*)d_in[2];
  const float* ln1_b    = (const float*)d_in[3];
  const float* ln2_g    = (const float*)d_in[4];
  const float* ln2_b    = (const float*)d_in[5];
  const float* sa_wq    = (const float*)d_in[6];
  const float* sa_wk    = (const float*)d_in[7];
  const float* sa_wv    = (const float*)d_in[8];
  const float* sa_wo    = (const float*)d_in[9];
  const float* sa_wo_b  = (const float*)d_in[10];
  const float* ff_ln_g  = (const float*)d_in[11];
  const float* ff_ln_b  = (const float*)d_in[12];
  const float* ff_w1    = (const float*)d_in[13];
  const float* ff_w2    = (const float*)d_in[14];
  const float* a_attn   = (const float*)d_in[15];
  const float* a_dense  = (const float*)d_in[16];
  const float* ca_wq    = (const float*)d_in[17];
  const float* ca_wk    = (const float*)d_in[18];
  const float* ca_wv    = (const float*)d_in[19];
  const float* ca_wo    = (const float*)d_in[20];
  const float* ca_wo_b  = (const float*)d_in[21];

  char* ws = (char*)d_ws;
  float*    x1     = (float*)(ws + WX1);
  float*    x2     = (float*)(ws + WX2);
  ushort_t* qkv_b  = (ushort_t*)(ws + WQKV);
  ushort_t* q2b    = (ushort_t*)(ws + WQKV);
  ushort_t* kv2b   = (ushort_t*)(ws + WQKV + 3145728u);
  ushort_t* comb_b = (ushort_t*)(ws + WBB1);
  ushort_t* attn_b = (ushort_t*)(ws + WBB1);
  ushort_t* tbuf_b = (ushort_t*)(ws + WBB1);
  ushort_t* g_b    = (ushort_t*)(ws + WG);
  ushort_t* hh     = (ushort_t*)(ws + WS1);
  ushort_t* x2b    = (ushort_t*)(ws + WS1);
  ushort_t* text_b = (ushort_t*)(ws + WTEXT);
  ushort_t* attn2b = (ushort_t*)(ws + WATT2);
  ushort_t* wqkv_t = (ushort_t*)(ws + WWQKV);
  ushort_t* wo_t   = (ushort_t*)(ws + WWO);
  ushort_t* w1_t   = (ushort_t*)(ws + WW1);
  ushort_t* w2_t   = (ushort_t*)(ws + WW2);
  ushort_t* cawq_t = (ushort_t*)(ws + WCAWQ);
  ushort_t* cakv_t = (ushort_t*)(ws + WCAKV);
  ushort_t* cawo_t = (ushort_t*)(ws + WCAWO);
  ushort_t* vt1    = (ushort_t*)(ws + WVT1);
  ushort_t* vt2    = (ushort_t*)(ws + WVT2);
  float* acc_wo  = (float*)(ws + WACC_WO);
  float* acc_ff2 = (float*)(ws + WACC_FF2);
  float* acc_q2  = (float*)(ws + WACC_Q2);
  float* acc_fin = (float*)(ws + WACC_FIN);
  float* out = (float*)d_out;

  const int Mc = B_DIM * NC_DIM;   // 2080
  const int Mx = B_DIM * N_DIM;    // 2048
  const int Mt = B_DIM * TEXT_LEN; // 154
  const int MNx = Mx * C_DIM;      // 1,572,864

  // ---- batched weight transposes ----
  WtDesc wd;
  const float* srcs[10] = {sa_wq, sa_wk, sa_wv, sa_wo, ca_wq, ca_wk, ca_wv, ca_wo, ff_w1, ff_w2};
  ushort_t* dsts[10] = {wqkv_t, wqkv_t + 589824, wqkv_t + 2 * 589824, wo_t,
                        cawq_t, cakv_t, cakv_t + 589824, cawo_t, w1_t, w2_t};
  int Ks[10] = {768, 768, 768, 768, 768, 768, 768, 768, 768, 3072};
  int Ns[10] = {768, 768, 768, 768, 768, 768, 768, 768, 6144, 768};
  int total = 0;
  for (int j = 0; j < 10; ++j) {
    wd.src[j] = srcs[j]; wd.dst[j] = dsts[j];
    wd.K[j] = Ks[j]; wd.N[j] = Ns[j];
    wd.tilesX[j] = Ns[j] / 64;
    wd.start[j] = total;
    total += (Ns[j] / 64) * (Ks[j] / 64);
  }
  wd.start[10] = total;   // 2880

  // wo-acc zero (WG region free until geglu writes g_b)
  hipMemsetAsync(ws + WACC_WO, 0, 6291456u, stream);
  wtrans_batched<<<total, 256, 0, stream>>>(wd);
  ln_concat_kernel<<<Mc, 256, 0, stream>>>(x, enc, ln1_g, ln1_b, comb_b);
  gemm_bf16<<<dim3(18, 17, 1), 256, 0, stream>>>(
      comb_b, wqkv_t, nullptr, qkv_b, nullptr, Mc, 2304, 768, 768,
      nullptr, nullptr, nullptr);
  vtrans_kernel<<<dim3(17, 12, B_DIM), 256, 0, stream>>>(
      qkv_b + 1536, vt1, NC_DIM, 2304, NC_DIM, 1088);
  attn_mfma<<<dim3(N_DIM / 64, 12, B_DIM), 256, 0, stream>>>(
      qkv_b + 0, qkv_b + 768, vt1, attn_b, NC_DIM, NC_DIM, NC_DIM, 1088, 2304, 2304);
  // ff2-acc zero (qkv_b dead now)
  hipMemsetAsync(ws + WACC_FF2, 0, 6291456u, stream);
  // wo: split-K 4 x 192
  gemm_bf16<<<dim3(6, 16, 4), 256, 0, stream>>>(
      attn_b, wo_t, nullptr, nullptr, acc_wo, Mx, 768, 768, 192,
      nullptr, nullptr, nullptr);
  splitk_epi<<<MNx / 1024, 256, 0, stream>>>(
      acc_wo, x1, nullptr, MNx, 768, sa_wo_b, x, a_attn);
  ln_double_kernel<<<Mx, 256, 0, stream>>>(x1, ln2_g, ln2_b, ff_ln_g, ff_ln_b, hh);
  gemm_bf16<<<dim3(48, 16, 1), 256, 0, stream>>>(
      hh, w1_t, nullptr, tbuf_b, nullptr, Mx, 6144, 768, 768,
      nullptr, nullptr, nullptr);
  geglu_kernel<<<(Mx * INNER) / 256, 256, 0, stream>>>(tbuf_b, g_b);
  // q2-acc + fin-acc zero (attn_b/tbuf_b dead now)
  hipMemsetAsync(ws + WACC_Q2, 0, 12582912u, stream);
  // ff2: split-K 6 x 512
  gemm_bf16<<<dim3(6, 16, 6), 256, 0, stream>>>(
      g_b, w2_t, nullptr, nullptr, acc_ff2, Mx, 768, 3072, 512,
      nullptr, nullptr, nullptr);
  splitk_epi<<<MNx / 1024, 256, 0, stream>>>(
      acc_ff2, x2, x2b, MNx, 768, nullptr, x1, a_dense);
  gather_text_kernel<<<Mt, 256, 0, stream>>>(enc, text_b);
  // q2: split-K 4 x 192
  gemm_bf16<<<dim3(6, 16, 4), 256, 0, stream>>>(
      x2b, cawq_t, nullptr, nullptr, acc_q2, Mx, 768, 768, 192,
      nullptr, nullptr, nullptr);
  splitk_epi<<<MNx / 1024, 256, 0, stream>>>(
      acc_q2, nullptr, q2b, MNx, 768, nullptr, nullptr, nullptr);
  gemm_bf16<<<dim3(12, 2, 1), 256, 0, stream>>>(
      text_b, cakv_t, nullptr, kv2b, nullptr, Mt, 1536, 768, 768,
      nullptr, nullptr, nullptr);
  vtrans_kernel<<<dim3(2, 12, B_DIM), 256, 0, stream>>>(
      kv2b + 768, vt2, TEXT_LEN, 1536, TEXT_LEN, 128);
  attn_mfma<<<dim3(N_DIM / 64, 12, B_DIM), 256, 0, stream>>>(
      q2b, kv2b + 0, vt2, attn2b, N_DIM, TEXT_LEN, TEXT_LEN, 128, 768, 1536);
  // final: split-K 4 x 192
  gemm_bf16<<<dim3(6, 16, 4), 256, 0, stream>>>(
      attn2b, cawo_t, nullptr, nullptr, acc_fin, Mx, 768, 768, 192,
      nullptr, nullptr, nullptr);
  splitk_epi<<<MNx / 1024, 256, 0, stream>>>(
      acc_fin, out, nullptr, MNx, 768, ca_wo_b, x2, nullptr);
}

// Round 6
// 387.204 us; speedup vs baseline: 6.6259x; 1.1673x over previous
//
#include <hip/hip_runtime.h>
#include <hip/hip_bf16.h>
#include <math.h>

// ---------------------------------------------------------------------------
// FaceAttnProcessor forward. R5: split-K via deterministic partial buffers
// (streamed stores + reduce epilogue) replacing fp32 atomics; wo-epilogue
// fused with double-LN. Attention = R3 MFMA flash.
// B=2, N=1024, C=768, H=12, d=64, INNER=3072.
// ---------------------------------------------------------------------------

#define C_DIM 768
#define B_DIM 2
#define N_DIM 1024
#define NC_DIM 1040
#define L_DIM 93
#define TEXT_LEN 77
#define INNER 3072

typedef unsigned short ushort_t;
typedef __bf16 bf16x8 __attribute__((ext_vector_type(8)));
typedef float f32x4 __attribute__((ext_vector_type(4)));

__device__ __forceinline__ ushort_t f2b(float f) {
  __hip_bfloat16 h = __float2bfloat16(f);
  return *(ushort_t*)&h;
}
__device__ __forceinline__ float b2f(ushort_t u) {
  __hip_bfloat16 h = *(__hip_bfloat16*)&u;
  return __bfloat162float(h);
}

__device__ __forceinline__ void g2lds16(const void* g, void* l) {
  __builtin_amdgcn_global_load_lds(
      (const __attribute__((address_space(1))) unsigned int*)g,
      (__attribute__((address_space(3))) unsigned int*)l, 16, 0, 0);
}

// ---------------- workspace map (byte offsets) ----------------------------
#define WX1    0u           // fp32 x1 (2048*768)
#define WX2    6291456u     // fp32 x2
#define WQKV   12582912u    // u16 qkv_b [2080][2304]; later q2b/kv2b
#define WBB1   22167552u    // u16 comb_b / attn_b / tbuf_b (25.17 MB region)
#define WG     47333376u    // u16 g_b [2048][3072]
#define WS1    59916288u    // u16 hh / x2b [2048][768]
#define WTEXT  63062016u    // u16 text_b [154][768]
#define WATT2  63298560u    // u16 attn2b [2048][768]
#define WWQKV  66444288u    // u16 wqkv_t [2304][768]
#define WWO    69983232u    // u16 wo_t   [768][768]
#define WW1    71162880u    // u16 w1_t   [6144][768]
#define WW2    80600064u    // u16 w2_t   [768][3072]
#define WCAWQ  85318656u    // u16 cawq_t [768][768]
#define WCAKV  86498304u    // u16 cakv_t [1536][768]
#define WCAWO  88857600u    // u16 cawo_t [768][768]
#define WVT1   90037248u    // u16 Vt self  [2][12][64][1088]
#define WVT2   93379584u    // u16 Vt cross [2][12][64][128]
// split-K partial slabs (6,291,456 B each, fp32 2048x768 per z):
//   wo  (z=3): after attn_b inside WBB1 (attn_b = 3,145,728 B live)
#define WPART_WO  (WBB1 + 3145728u)     // 18.9 MB, ends < WG
//   ff2 (z=4): whole WBB1 region (attn_b/tbuf_b dead)        = 25,165,824 B
#define WPART_FF2 WBB1
//   q2  (z=3): WBB1 region again (free after ff2 epilogue)
#define WPART_Q2  WBB1
//   fin (z=3): WBB1 region again (free after q2 epilogue)
#define WPART_FIN WBB1
// end: 93,772,800 B

// ---------------- block reduction (256 threads = 4 waves) -----------------
__device__ __forceinline__ float block_sum(float v, float* sh) {
#pragma unroll
  for (int o = 32; o > 0; o >>= 1) v += __shfl_down(v, o);
  int lane = threadIdx.x & 63, w = threadIdx.x >> 6;
  if (lane == 0) sh[w] = v;
  __syncthreads();
  float r = sh[0] + sh[1] + sh[2] + sh[3];
  __syncthreads();
  return r;
}

// ---------------- batched weight cast+transpose ---------------------------
struct WtDesc {
  const float* src[10];
  ushort_t*    dst[10];
  int K[10];
  int N[10];
  int tilesX[10];
  int start[11];
};

__global__ __launch_bounds__(256)
void wtrans_batched(WtDesc d) {
  __shared__ float tile[64][65];
  int bid = blockIdx.x;
  int j = 0;
  while (j < 9 && bid >= d.start[j + 1]) ++j;
  int ti = bid - d.start[j];
  int K = d.K[j], N = d.N[j];
  int n0 = (ti % d.tilesX[j]) * 64, k0 = (ti / d.tilesX[j]) * 64;
  const float* in = d.src[j];
  ushort_t* out = d.dst[j];
  int t = threadIdx.x;
#pragma unroll
  for (int p = 0; p < 16; ++p) {
    int idx = t + p * 256;
    int r = idx >> 6, c = idx & 63;
    tile[r][c] = in[(size_t)(k0 + r) * N + n0 + c];
  }
  __syncthreads();
#pragma unroll
  for (int p = 0; p < 16; ++p) {
    int idx = t + p * 256;
    int r = idx >> 6, c = idx & 63;
    out[(size_t)(n0 + r) * K + k0 + c] = f2b(tile[c][r]);
  }
}

// ---------------- LN(x) and LN(face) -> comb (bf16) -----------------------
__global__ __launch_bounds__(256)
void ln_concat_kernel(const float* __restrict__ x, const float* __restrict__ enc,
                      const float* __restrict__ g, const float* __restrict__ b,
                      ushort_t* __restrict__ comb) {
  __shared__ float sh[4];
  int r = blockIdx.x;
  int bb = r / NC_DIM, i = r % NC_DIM;
  const float* src = (i < N_DIM)
      ? (x   + ((size_t)bb * N_DIM + i) * C_DIM)
      : (enc + ((size_t)bb * L_DIM + TEXT_LEN + (i - N_DIM)) * C_DIM);
  float v[3];
#pragma unroll
  for (int j = 0; j < 3; ++j) v[j] = src[threadIdx.x + j * 256];
  float mean = block_sum(v[0] + v[1] + v[2], sh) * (1.f / C_DIM);
  float sq = 0.f;
#pragma unroll
  for (int j = 0; j < 3; ++j) { float d = v[j] - mean; sq += d * d; }
  float rstd = rsqrtf(block_sum(sq, sh) * (1.f / C_DIM) + 1e-5f);
  ushort_t* dst = comb + (size_t)r * C_DIM;
#pragma unroll
  for (int j = 0; j < 3; ++j) {
    int c = threadIdx.x + j * 256;
    dst[c] = f2b((v[j] - mean) * rstd * g[c] + b[c]);
  }
}

// ---------------- bf16 MFMA GEMM, double-buffered, optional split-K --------
// grid.z = nz; block covers K range [z*Ksplit, min(K,(z+1)*Ksplit)).
// Part != null: streamed fp32 partial stores to Part[z*M*N + ...] (reduce
// done by epilogue kernels). Part == null: fused epilogue.
__global__ __launch_bounds__(256)
void gemm_bf16(const ushort_t* __restrict__ A, const ushort_t* __restrict__ Bt,
               float* __restrict__ Out, ushort_t* __restrict__ Ob,
               float* __restrict__ Part,
               int M, int N, int K, int Ksplit,
               const float* __restrict__ bias, const float* __restrict__ res,
               const float* __restrict__ alphaPtr) {
  __shared__ ushort_t sA[2][128 * 32];
  __shared__ ushort_t sB[2][128 * 32];
  int t = threadIdx.x;
  int w = t >> 6, ln = t & 63;
  int m0 = blockIdx.y * 128, n0 = blockIdx.x * 128;
  int wm = (w >> 1) * 64, wn = (w & 1) * 64;
  int lr = ln & 15, lq = ln >> 4;
  int seg_r = ln >> 2, seg_c = (ln & 3) * 8;
  int kbeg = blockIdx.z * Ksplit;
  int kend = kbeg + Ksplit; if (kend > K) kend = K;

  f32x4 acc[4][4];
#pragma unroll
  for (int mi = 0; mi < 4; ++mi)
#pragma unroll
    for (int ni = 0; ni < 4; ++ni) acc[mi][ni] = (f32x4){0.f, 0.f, 0.f, 0.f};

#define STAGE(k0_, buf_)                                                     \
  do {                                                                       \
    _Pragma("unroll") for (int l = 0; l < 2; ++l) {                          \
      int s = w * 2 + l;                                                     \
      int arow = m0 + s * 16 + seg_r;                                        \
      arow = arow < M ? arow : M - 1;                                        \
      g2lds16(A + (size_t)arow * K + (k0_) + seg_c, &sA[buf_][s * 512]);     \
      int nrow = n0 + s * 16 + seg_r;                                        \
      g2lds16(Bt + (size_t)nrow * K + (k0_) + seg_c, &sB[buf_][s * 512]);    \
    }                                                                        \
  } while (0)

  STAGE(kbeg, 0);
  __syncthreads();
  int cur = 0;
  for (int k0 = kbeg; k0 < kend; k0 += 32) {
    if (k0 + 32 < kend) STAGE(k0 + 32, cur ^ 1);   // prefetch next tile
    bf16x8 af[4], bfr[4];
#pragma unroll
    for (int mi = 0; mi < 4; ++mi)
      af[mi] = *(const bf16x8*)&sA[cur][(wm + mi * 16 + lr) * 32 + lq * 8];
#pragma unroll
    for (int ni = 0; ni < 4; ++ni)
      bfr[ni] = *(const bf16x8*)&sB[cur][(wn + ni * 16 + lr) * 32 + lq * 8];
#pragma unroll
    for (int mi = 0; mi < 4; ++mi)
#pragma unroll
      for (int ni = 0; ni < 4; ++ni)
        acc[mi][ni] = __builtin_amdgcn_mfma_f32_16x16x32_bf16(
            af[mi], bfr[ni], acc[mi][ni], 0, 0, 0);
    __syncthreads();
    cur ^= 1;
  }
#undef STAGE

  if (Part) {
    float* P = Part + (size_t)blockIdx.z * M * N;
#pragma unroll
    for (int mi = 0; mi < 4; ++mi)
#pragma unroll
      for (int ni = 0; ni < 4; ++ni) {
        int col = n0 + wn + ni * 16 + lr;
#pragma unroll
        for (int r = 0; r < 4; ++r) {
          int row = m0 + wm + mi * 16 + lq * 4 + r;
          if (row < M) P[(size_t)row * N + col] = acc[mi][ni][r];
        }
      }
  } else {
    float f = alphaPtr ? tanhf(alphaPtr[0]) : 1.0f;
#pragma unroll
    for (int mi = 0; mi < 4; ++mi)
#pragma unroll
      for (int ni = 0; ni < 4; ++ni) {
        int col = n0 + wn + ni * 16 + lr;
        float bv = bias ? bias[col] : 0.f;
#pragma unroll
        for (int r = 0; r < 4; ++r) {
          int row = m0 + wm + mi * 16 + lq * 4 + r;
          if (row < M) {
            float val = acc[mi][ni][r] + bv;
            if (res) val = res[(size_t)row * N + col] + f * val;
            if (Out) Out[(size_t)row * N + col] = val;
            if (Ob)  Ob[(size_t)row * N + col] = f2b(val);
          }
        }
      }
  }
}

// ---------------- split-K reduce epilogue ----------------------------------
// Sums nz partial slabs, applies bias/res/alpha, writes fp32/bf16 outputs.
__global__ __launch_bounds__(256)
void splitk_epi(const float* __restrict__ Part, int nz, float* __restrict__ Out,
                ushort_t* __restrict__ Ob, int MN, int N,
                const float* __restrict__ bias, const float* __restrict__ res,
                const float* __restrict__ alphaPtr) {
  int idx = (blockIdx.x * 256 + threadIdx.x) * 4;
  if (idx >= MN) return;
  float f = alphaPtr ? tanhf(alphaPtr[0]) : 1.0f;
  float v[4] = {0.f, 0.f, 0.f, 0.f};
  for (int z = 0; z < nz; ++z) {
    float4 a = *(const float4*)&Part[(size_t)z * MN + idx];
    v[0] += a.x; v[1] += a.y; v[2] += a.z; v[3] += a.w;
  }
  if (bias) {
    int col = idx % N;
    float4 bb = *(const float4*)&bias[col];
    v[0] += bb.x; v[1] += bb.y; v[2] += bb.z; v[3] += bb.w;
  }
  if (res) {
    float4 rr = *(const float4*)&res[idx];
    v[0] = rr.x + f * v[0]; v[1] = rr.y + f * v[1];
    v[2] = rr.z + f * v[2]; v[3] = rr.w + f * v[3];
  }
  if (Out) *(float4*)&Out[idx] = make_float4(v[0], v[1], v[2], v[3]);
  if (Ob) {
    ushort4 o;
    o.x = f2b(v[0]); o.y = f2b(v[1]); o.z = f2b(v[2]); o.w = f2b(v[3]);
    *(ushort4*)&Ob[idx] = o;
  }
}

// ---------------- fused wo-epilogue + double layernorm --------------------
// One block per row: x1 = x + tanh(a)*(sum_z Part + bias); hh = LN(LN(x1)).
__global__ __launch_bounds__(256)
void woepi_ln_kernel(const float* __restrict__ Part, int nz,
                     const float* __restrict__ bias, const float* __restrict__ xres,
                     const float* __restrict__ alphaPtr, float* __restrict__ x1,
                     const float* __restrict__ g1, const float* __restrict__ b1,
                     const float* __restrict__ g2, const float* __restrict__ b2,
                     ushort_t* __restrict__ hh) {
  __shared__ float sh[4];
  int row = blockIdx.x;
  const int MN = B_DIM * N_DIM * C_DIM;
  float f = tanhf(alphaPtr[0]);
  float v[3];
#pragma unroll
  for (int j = 0; j < 3; ++j) {
    int c = threadIdx.x + j * 256;
    float s = 0.f;
    for (int z = 0; z < nz; ++z) s += Part[(size_t)z * MN + (size_t)row * C_DIM + c];
    s += bias[c];
    float xv = xres[(size_t)row * C_DIM + c] + f * s;
    x1[(size_t)row * C_DIM + c] = xv;
    v[j] = xv;
  }
  float mean = block_sum(v[0] + v[1] + v[2], sh) * (1.f / C_DIM);
  float sq = 0.f;
#pragma unroll
  for (int j = 0; j < 3; ++j) { float d = v[j] - mean; sq += d * d; }
  float rstd = rsqrtf(block_sum(sq, sh) * (1.f / C_DIM) + 1e-5f);
  float y[3];
#pragma unroll
  for (int j = 0; j < 3; ++j) {
    int c = threadIdx.x + j * 256;
    y[j] = (v[j] - mean) * rstd * g1[c] + b1[c];
  }
  float mean2 = block_sum(y[0] + y[1] + y[2], sh) * (1.f / C_DIM);
  sq = 0.f;
#pragma unroll
  for (int j = 0; j < 3; ++j) { float d = y[j] - mean2; sq += d * d; }
  float rstd2 = rsqrtf(block_sum(sq, sh) * (1.f / C_DIM) + 1e-5f);
#pragma unroll
  for (int j = 0; j < 3; ++j) {
    int c = threadIdx.x + j * 256;
    hh[(size_t)row * C_DIM + c] = f2b((y[j] - mean2) * rstd2 * g2[c] + b2[c]);
  }
}

// ---------------- V transpose: strided bf16 [key][64] -> Vt [dv][Nkp] -----
__global__ __launch_bounds__(256)
void vtrans_kernel(const ushort_t* __restrict__ V, ushort_t* __restrict__ Vt,
                   int rows_per_b, int stride, int Nk, int Nkp) {
  __shared__ ushort_t tile[64][68];
  int k0 = blockIdx.x * 64;
  int h = blockIdx.y, b = blockIdx.z;
  int t = threadIdx.x;
#pragma unroll
  for (int p = 0; p < 4; ++p) {
    int r = p * 16 + (t >> 4), c = (t & 15) * 4;
    int key = k0 + r;
    ushort4 u = make_ushort4(0, 0, 0, 0);
    if (key < Nk)
      u = *(const ushort4*)&V[((size_t)(b * rows_per_b + key)) * stride + h * 64 + c];
    *(ushort4*)&tile[r][c] = u;
  }
  __syncthreads();
  size_t base = ((size_t)(b * 12 + h)) * 64 * Nkp;
#pragma unroll
  for (int p = 0; p < 4; ++p) {
    int dv = p * 16 + (t >> 4), kc = (t & 15) * 4;
    ushort4 u;
    u.x = tile[kc + 0][dv]; u.y = tile[kc + 1][dv];
    u.z = tile[kc + 2][dv]; u.w = tile[kc + 3][dv];
    *(ushort4*)&Vt[base + (size_t)dv * Nkp + k0 + kc] = u;
  }
}

// ---------------- MFMA flash attention (R3, unchanged) --------------------
__global__ __launch_bounds__(256)
void attn_mfma(const ushort_t* __restrict__ Q, const ushort_t* __restrict__ K,
               const ushort_t* __restrict__ Vt, ushort_t* __restrict__ O,
               int q_rows_per_b, int kv_rows_per_b, int Nk, int Nkp,
               int qstride, int kstride) {
  __shared__ ushort_t sQ[2 * 64 * 32];
  __shared__ ushort_t sK[2 * 64 * 32];
  __shared__ ushort_t sV[2 * 64 * 32];
  __shared__ ushort_t sP[4][2 * 16 * 32];
  const float scale = 0.125f;
  int t = threadIdx.x;
  int w = t >> 6, ln = t & 63;
  int col = ln & 15, quad = ln >> 4;
  int b = blockIdx.z, h = blockIdx.y, q0 = blockIdx.x * 64;

#pragma unroll
  for (int s = 0; s < 2; ++s) {
    int r = q0 + w * 16 + (ln >> 2);
    const ushort_t* gp = Q + (size_t)(b * q_rows_per_b + r) * qstride
                       + h * 64 + s * 32 + (ln & 3) * 8;
    g2lds16(gp, (char*)sQ + s * 4096 + w * 1024);
  }
  __syncthreads();
  bf16x8 qa[2];
#pragma unroll
  for (int s = 0; s < 2; ++s)
    qa[s] = *(const bf16x8*)&sQ[s * 2048 + (w * 16 + col) * 32 + quad * 8];

  f32x4 oacc[4];
#pragma unroll
  for (int i = 0; i < 4; ++i) oacc[i] = (f32x4){0.f, 0.f, 0.f, 0.f};
  float m_i[4], l_i[4];
#pragma unroll
  for (int r = 0; r < 4; ++r) { m_i[r] = -1e30f; l_i[r] = 0.f; }

  ushort_t* sPw = sP[w];
  size_t vt_base = ((size_t)(b * 12 + h)) * 64 * Nkp;
  int ntiles = Nkp >> 6;

  for (int kt = 0; kt < ntiles; ++kt) {
    __syncthreads();
#pragma unroll
    for (int s = 0; s < 2; ++s) {
      int key = kt * 64 + w * 16 + (ln >> 2);
      const ushort_t* gp = K + (size_t)(b * kv_rows_per_b + key) * kstride
                         + h * 64 + s * 32 + (ln & 3) * 8;
      g2lds16(gp, (char*)sK + s * 4096 + w * 1024);
    }
#pragma unroll
    for (int s = 0; s < 2; ++s) {
      int dv = w * 16 + (ln >> 2);
      const ushort_t* gp = Vt + vt_base + (size_t)dv * Nkp
                         + kt * 64 + s * 32 + (ln & 3) * 8;
      g2lds16(gp, (char*)sV + s * 4096 + w * 1024);
    }
    __syncthreads();

    f32x4 cs[4];
#pragma unroll
    for (int nblk = 0; nblk < 4; ++nblk) {
      cs[nblk] = (f32x4){0.f, 0.f, 0.f, 0.f};
#pragma unroll
      for (int s = 0; s < 2; ++s) {
        bf16x8 kb = *(const bf16x8*)&sK[s * 2048 + (nblk * 16 + col) * 32 + quad * 8];
        cs[nblk] = __builtin_amdgcn_mfma_f32_16x16x32_bf16(qa[s], kb, cs[nblk], 0, 0, 0);
      }
    }
#pragma unroll
    for (int nblk = 0; nblk < 4; ++nblk) {
      bool valid = (kt * 64 + nblk * 16 + col) < Nk;
#pragma unroll
      for (int r = 0; r < 4; ++r)
        cs[nblk][r] = valid ? cs[nblk][r] * scale : -1e30f;
    }
#pragma unroll
    for (int r = 0; r < 4; ++r) {
      float rm = fmaxf(fmaxf(cs[0][r], cs[1][r]), fmaxf(cs[2][r], cs[3][r]));
#pragma unroll
      for (int o = 1; o < 16; o <<= 1) rm = fmaxf(rm, __shfl_xor(rm, o));
      float mnew = fmaxf(m_i[r], rm);
      float alpha = __expf(m_i[r] - mnew);
      float ps = 0.f;
#pragma unroll
      for (int nblk = 0; nblk < 4; ++nblk) {
        float p = __expf(cs[nblk][r] - mnew);
        cs[nblk][r] = p; ps += p;
      }
#pragma unroll
      for (int o = 1; o < 16; o <<= 1) ps += __shfl_xor(ps, o);
      l_i[r] = l_i[r] * alpha + ps;
      m_i[r] = mnew;
#pragma unroll
      for (int nblk = 0; nblk < 4; ++nblk) oacc[nblk][r] *= alpha;
    }
#pragma unroll
    for (int nblk = 0; nblk < 4; ++nblk) {
      int s = nblk >> 1, kin = (nblk & 1) * 16 + col;
#pragma unroll
      for (int r = 0; r < 4; ++r)
        sPw[s * 512 + (quad * 4 + r) * 32 + kin] = f2b(cs[nblk][r]);
    }
#pragma unroll
    for (int s = 0; s < 2; ++s) {
      bf16x8 pa = *(const bf16x8*)&sPw[s * 512 + col * 32 + quad * 8];
#pragma unroll
      for (int nblk = 0; nblk < 4; ++nblk) {
        bf16x8 vb = *(const bf16x8*)&sV[s * 2048 + (nblk * 16 + col) * 32 + quad * 8];
        oacc[nblk] = __builtin_amdgcn_mfma_f32_16x16x32_bf16(pa, vb, oacc[nblk], 0, 0, 0);
      }
    }
  }

#pragma unroll
  for (int r = 0; r < 4; ++r) {
    float inv = 1.f / l_i[r];
    int row = b * N_DIM + q0 + w * 16 + quad * 4 + r;
#pragma unroll
    for (int nblk = 0; nblk < 4; ++nblk)
      O[(size_t)row * C_DIM + h * 64 + nblk * 16 + col] = f2b(oacc[nblk][r] * inv);
  }
}

// ---------------- GEGLU ----------------------------------------------------
__global__ __launch_bounds__(256)
void geglu_kernel(const ushort_t* __restrict__ tbuf, ushort_t* __restrict__ g) {
  int idx = blockIdx.x * 256 + threadIdx.x;
  int r = idx / INNER, c = idx % INNER;
  float a = b2f(tbuf[(size_t)r * (2 * INNER) + c]);
  float x = b2f(tbuf[(size_t)r * (2 * INNER) + INNER + c]);
  float ge = 0.5f * x * (1.f + erff(x * 0.70710678118654752f));
  g[idx] = f2b(a * ge);
}

// ---------------- text gather ----------------------------------------------
__global__ __launch_bounds__(256)
void gather_text_kernel(const float* __restrict__ enc, ushort_t* __restrict__ out) {
  int r = blockIdx.x;
  int bb = r / TEXT_LEN, j = r % TEXT_LEN;
  const float* src = enc + ((size_t)bb * L_DIM + j) * C_DIM;
  ushort_t* dst = out + (size_t)r * C_DIM;
#pragma unroll
  for (int l = 0; l < 3; ++l) {
    int c = threadIdx.x + l * 256;
    dst[c] = f2b(src[c]);
  }
}

// ---------------------------------------------------------------------------
extern "C" void kernel_launch(void* const* d_in, const int* in_sizes, int n_in,
                              void* d_out, int out_size, void* d_ws, size_t ws_size,
                              hipStream_t stream) {
  const float* x        = (const float*)d_in[0];
  const float* enc      = (const float*)d_in[1];
  const float* ln1_g    = (const float*)d_in[2];
  const float* ln1_b    = (const float*)d_in[3];
  const float* ln2_g    = (const float*)d_in[4];
  const float* ln2_b    = (const float*)d_in[5];
  const float* sa_wq    = (const float*)d_in[6];
  const float* sa_wk    = (const float*)d_in[7];
  const float* sa_wv    = (const float*)d_in[8];
  const float* sa_wo    = (const float*)d_in[9];
  const float* sa_wo_b  = (const float*)d_in[10];
  const float* ff_ln_g  = (const float*)d_in[11];
  const float* ff_ln_b  = (const float*)d_in[12];
  const float* ff_w1    = (const float*)d_in[13];
  const float* ff_w2    = (const float*)d_in[14];
  const float* a_attn   = (const float*)d_in[15];
  const float* a_dense  = (const float*)d_in[16];
  const float* ca_wq    = (const float*)d_in[17];
  const float* ca_wk    = (const float*)d_in[18];
  const float* ca_wv    = (const float*)d_in[19];
  const float* ca_wo    = (const float*)d_in[20];
  const float* ca_wo_b  = (const float*)d_in[21];

  char* ws = (char*)d_ws;
  float*    x1     = (float*)(ws + WX1);
  float*    x2     = (float*)(ws + WX2);
  ushort_t* qkv_b  = (ushort_t*)(ws + WQKV);
  ushort_t* q2b    = (ushort_t*)(ws + WQKV);
  ushort_t* kv2b   = (ushort_t*)(ws + WQKV + 3145728u);
  ushort_t* comb_b = (ushort_t*)(ws + WBB1);
  ushort_t* attn_b = (ushort_t*)(ws + WBB1);
  ushort_t* tbuf_b = (ushort_t*)(ws + WBB1);
  ushort_t* g_b    = (ushort_t*)(ws + WG);
  ushort_t* hh     = (ushort_t*)(ws + WS1);
  ushort_t* x2b    = (ushort_t*)(ws + WS1);
  ushort_t* text_b = (ushort_t*)(ws + WTEXT);
  ushort_t* attn2b = (ushort_t*)(ws + WATT2);
  ushort_t* wqkv_t = (ushort_t*)(ws + WWQKV);
  ushort_t* wo_t   = (ushort_t*)(ws + WWO);
  ushort_t* w1_t   = (ushort_t*)(ws + WW1);
  ushort_t* w2_t   = (ushort_t*)(ws + WW2);
  ushort_t* cawq_t = (ushort_t*)(ws + WCAWQ);
  ushort_t* cakv_t = (ushort_t*)(ws + WCAKV);
  ushort_t* cawo_t = (ushort_t*)(ws + WCAWO);
  ushort_t* vt1    = (ushort_t*)(ws + WVT1);
  ushort_t* vt2    = (ushort_t*)(ws + WVT2);
  float* part_wo  = (float*)(ws + WPART_WO);
  float* part_ff2 = (float*)(ws + WPART_FF2);
  float* part_q2  = (float*)(ws + WPART_Q2);
  float* part_fin = (float*)(ws + WPART_FIN);
  float* out = (float*)d_out;

  const int Mc = B_DIM * NC_DIM;   // 2080
  const int Mx = B_DIM * N_DIM;    // 2048
  const int Mt = B_DIM * TEXT_LEN; // 154
  const int MNx = Mx * C_DIM;      // 1,572,864

  // ---- batched weight transposes ----
  WtDesc wd;
  const float* srcs[10] = {sa_wq, sa_wk, sa_wv, sa_wo, ca_wq, ca_wk, ca_wv, ca_wo, ff_w1, ff_w2};
  ushort_t* dsts[10] = {wqkv_t, wqkv_t + 589824, wqkv_t + 2 * 589824, wo_t,
                        cawq_t, cakv_t, cakv_t + 589824, cawo_t, w1_t, w2_t};
  int Ks[10] = {768, 768, 768, 768, 768, 768, 768, 768, 768, 3072};
  int Ns[10] = {768, 768, 768, 768, 768, 768, 768, 768, 6144, 768};
  int total = 0;
  for (int j = 0; j < 10; ++j) {
    wd.src[j] = srcs[j]; wd.dst[j] = dsts[j];
    wd.K[j] = Ks[j]; wd.N[j] = Ns[j];
    wd.tilesX[j] = Ns[j] / 64;
    wd.start[j] = total;
    total += (Ns[j] / 64) * (Ks[j] / 64);
  }
  wd.start[10] = total;   // 2880

  wtrans_batched<<<total, 256, 0, stream>>>(wd);
  ln_concat_kernel<<<Mc, 256, 0, stream>>>(x, enc, ln1_g, ln1_b, comb_b);
  gemm_bf16<<<dim3(18, 17, 1), 256, 0, stream>>>(
      comb_b, wqkv_t, nullptr, qkv_b, nullptr, Mc, 2304, 768, 768,
      nullptr, nullptr, nullptr);
  vtrans_kernel<<<dim3(17, 12, B_DIM), 256, 0, stream>>>(
      qkv_b + 1536, vt1, NC_DIM, 2304, NC_DIM, 1088);
  attn_mfma<<<dim3(N_DIM / 64, 12, B_DIM), 256, 0, stream>>>(
      qkv_b + 0, qkv_b + 768, vt1, attn_b, NC_DIM, NC_DIM, NC_DIM, 1088, 2304, 2304);
  // wo: split-K 3 x 256 -> partials -> fused epilogue+double-LN
  gemm_bf16<<<dim3(6, 16, 3), 256, 0, stream>>>(
      attn_b, wo_t, nullptr, nullptr, part_wo, Mx, 768, 768, 256,
      nullptr, nullptr, nullptr);
  woepi_ln_kernel<<<Mx, 256, 0, stream>>>(
      part_wo, 3, sa_wo_b, x, a_attn, x1, ln2_g, ln2_b, ff_ln_g, ff_ln_b, hh);
  gemm_bf16<<<dim3(48, 16, 1), 256, 0, stream>>>(
      hh, w1_t, nullptr, tbuf_b, nullptr, Mx, 6144, 768, 768,
      nullptr, nullptr, nullptr);
  geglu_kernel<<<(Mx * INNER) / 256, 256, 0, stream>>>(tbuf_b, g_b);
  // ff2: split-K 4 x 768 (partials overlay WBB1; tbuf_b dead after geglu)
  gemm_bf16<<<dim3(6, 16, 4), 256, 0, stream>>>(
      g_b, w2_t, nullptr, nullptr, part_ff2, Mx, 768, 3072, 768,
      nullptr, nullptr, nullptr);
  splitk_epi<<<MNx / 1024, 256, 0, stream>>>(
      part_ff2, 4, x2, x2b, MNx, 768, nullptr, x1, a_dense);
  gather_text_kernel<<<Mt, 256, 0, stream>>>(enc, text_b);
  // q2: split-K 3 x 256
  gemm_bf16<<<dim3(6, 16, 3), 256, 0, stream>>>(
      x2b, cawq_t, nullptr, nullptr, part_q2, Mx, 768, 768, 256,
      nullptr, nullptr, nullptr);
  splitk_epi<<<MNx / 1024, 256, 0, stream>>>(
      part_q2, 3, nullptr, q2b, MNx, 768, nullptr, nullptr, nullptr);
  gemm_bf16<<<dim3(12, 2, 1), 256, 0, stream>>>(
      text_b, cakv_t, nullptr, kv2b, nullptr, Mt, 1536, 768, 768,
      nullptr, nullptr, nullptr);
  vtrans_kernel<<<dim3(2, 12, B_DIM), 256, 0, stream>>>(
      kv2b + 768, vt2, TEXT_LEN, 1536, TEXT_LEN, 128);
  attn_mfma<<<dim3(N_DIM / 64, 12, B_DIM), 256, 0, stream>>>(
      q2b, kv2b + 0, vt2, attn2b, N_DIM, TEXT_LEN, TEXT_LEN, 128, 768, 1536);
  // final: split-K 3 x 256
  gemm_bf16<<<dim3(6, 16, 3), 256, 0, stream>>>(
      attn2b, cawo_t, nullptr, nullptr, part_fin, Mx, 768, 768, 256,
      nullptr, nullptr, nullptr);
  splitk_epi<<<MNx / 1024, 256, 0, stream>>>(
      part_fin, 3, out, nullptr, MNx, 768, ca_wo_b, x2, nullptr);
}